// Round 6
// baseline (2812.612 us; speedup 1.0000x reference)
//
#include <hip/hip_runtime.h>

#define NB 512
#define NT 256
#define NI 32
#define NH 128
#define NG 512

#define L2E  1.4426950408889634f
#define L2E2 2.8853900817779268f

typedef __attribute__((ext_vector_type(8))) short bf16x8;
typedef __attribute__((ext_vector_type(4))) float f32x4;
typedef unsigned long long u64;

__device__ __forceinline__ unsigned short f2bf_rne(float f) {
    unsigned u = __float_as_uint(f);
    return (unsigned short)((u + 0x7FFFu + ((u >> 16) & 1u)) >> 16);
}
__device__ __forceinline__ void split2(float a, float b, unsigned& hi, unsigned& lo) {
    unsigned short ha = f2bf_rne(a), hb = f2bf_rne(b);
    float ra = a - __uint_as_float((unsigned)ha << 16);
    float rb = b - __uint_as_float((unsigned)hb << 16);
    hi = (unsigned)ha | ((unsigned)hb << 16);
    lo = (unsigned)f2bf_rne(ra) | ((unsigned)f2bf_rne(rb) << 16);
}
__device__ __forceinline__ bf16x8 u4bf(uint4 u) {
    union { uint4 u; bf16x8 v; } c; c.u = u; return c.v;
}
#define MFMA16(accv, av, bv) \
    accv = __builtin_amdgcn_mfma_f32_16x16x32_bf16(av, bv, accv, 0, 0, 0)

__device__ __forceinline__ void lds_barrier() {
    asm volatile("s_waitcnt lgkmcnt(0)\n\ts_barrier" ::: "memory");
}
__device__ __forceinline__ void vm_drain() {
    asm volatile("s_waitcnt vmcnt(0)" ::: "memory");
}

// AGENT-scope relaxed atomics: each access goes to the coherence point (LLC),
// cross-XCD safe with NO fences and NO L2 writebacks.
__device__ __forceinline__ u64 ald64(const u64* p) {
    return __hip_atomic_load(p, __ATOMIC_RELAXED, __HIP_MEMORY_SCOPE_AGENT);
}
__device__ __forceinline__ void ast64(u64* p, u64 v) {
    __hip_atomic_store(p, v, __ATOMIC_RELAXED, __HIP_MEMORY_SCOPE_AGENT);
}
__device__ __forceinline__ unsigned aldu(const unsigned* p) {
    return __hip_atomic_load(p, __ATOMIC_RELAXED, __HIP_MEMORY_SCOPE_AGENT);
}
__device__ __forceinline__ void astu(unsigned* p, unsigned v) {
    __hip_atomic_store(p, v, __ATOMIC_RELAXED, __HIP_MEMORY_SCOPE_AGENT);
}

// fused activation: inputs m_* = -(log2e-scaled preact); updates c, returns h
__device__ __forceinline__ float activ(float mi, float mf, float mg, float mo,
                                       float& c) {
    float ei = exp2f(mi), ef = exp2f(mf), eg = exp2f(mg), eo = exp2f(mo);
    float rf  = __builtin_amdgcn_rcpf(1.0f + ef);
    float rig = __builtin_amdgcn_rcpf((1.0f + ei) * (1.0f + eg));
    float cn  = c * rf + (1.0f - eg) * rig;
    c = cn;
    float ec = exp2f(cn * -L2E2);
    float rh = __builtin_amdgcn_rcpf((1.0f + eo) * (1.0f + ec));
    return (1.0f - ec) * rh;
}

// ---------------------------------------------------------------------------
// R20: two-role persistent kernel, NO GEMM middleman.
//  blocks  0-31 (role0): layer-0 recurrence, x.W_ih0 fused; exports h0_t as
//    split-bf16 planes (2 b64 AGENT stores/thread/step); ctr0[p] every 4 steps.
//  blocks 32-63 (role1): layer-1 recurrence computing BOTH matmuls per step:
//    gates = -(scaled)(W_ih1.h0_t + W_hh1.h1_{t-1} + b). h0_t staged from the
//    LLC planes into double-buffered LDS tiles (2 b64 atomic loads/thread/step,
//    prefetched 2 steps deep), then fragment-read like the h1 exchange.
// R19's counters showed 785 MB of LLC traffic (268 MB xg written + 268 read
// via 8B atomics + ring/poll overhead) pacing the step at 2.6us. This design
// moves only the h0 planes (67 MB each way) -> ~5x less message traffic,
// at the cost of +48 MFMA/wave/step in role1 (issue ~931 cyc/SIMD, fits).
// Dependency role0 -> role1 is acyclic: deadlock-free.
// ---------------------------------------------------------------------------
__global__ __launch_bounds__(512, 1)
void fused(const float* __restrict__ x,
           const float* __restrict__ w_hh0, const float* __restrict__ w_hh1,
           const float* __restrict__ w_ih0, const float* __restrict__ b_ih0,
           const float* __restrict__ b_hh0,
           const float* __restrict__ w_ih1, const float* __restrict__ b_ih1,
           const float* __restrict__ b_hh1,
           const float* __restrict__ fc1w, const float* __restrict__ fc1b,
           const float* __restrict__ fc2w, const float* __restrict__ fc2b,
           u64* __restrict__ h0pl,          // [256][2][32][512] u64 planes
           float* __restrict__ h1s, float* __restrict__ out,
           unsigned* __restrict__ ctr0)
{
    __shared__ __align__(16) unsigned short HA[2][16][128];   // h exchange
    __shared__ __align__(16) unsigned short HL[2][16][128];
    __shared__ __align__(16) unsigned short GH[2][16][128];   // role1: h0 tiles
    __shared__ __align__(16) unsigned short GL[2][16][128];

    const int bid  = blockIdx.x;
    const int tid  = threadIdx.x;
    const int wv   = tid >> 6;
    const int lane = tid & 63;
    const int quad = lane >> 4;
    const int ml   = lane & 15;
    const int role = bid >> 5;
    const int p    = bid & 31;
    const int j    = 16 * wv + ml;
    const float* wsrc = role ? w_hh1 : w_hh0;

    // ---- stage W_hh (log2e-prescaled) hi+lo in registers ----
    bf16x8 wh[4][4], wl[4][4];
#pragma unroll
    for (int t = 0; t < 4; ++t) {
        const float sc = (t == 2) ? L2E2 : L2E;
#pragma unroll
        for (int q = 0; q < 4; ++q) {
            int n = (t * 8 + wv) * 16 + ml;
            const float* s = wsrc + (size_t)n * NH + q * 32 + quad * 8;
            float4 v0 = *(const float4*)s;
            float4 v1 = *(const float4*)(s + 4);
            uint4 H, L;
            split2(v0.x * sc, v0.y * sc, H.x, L.x); split2(v0.z * sc, v0.w * sc, H.y, L.y);
            split2(v1.x * sc, v1.y * sc, H.z, L.z); split2(v1.z * sc, v1.w * sc, H.w, L.w);
            wh[t][q] = u4bf(H);
            wl[t][q] = u4bf(L);
        }
    }

    int ro[4];
#pragma unroll
    for (int q = 0; q < 4; ++q)
        ro[q] = ((ml * 256 + q * 64 + quad * 16) ^ ((ml & 7) << 4));
    int wo[4];
#pragma unroll
    for (int r = 0; r < 4; ++r) {
        int m = quad * 4 + r;
        wo[r] = ((m * 256 + j * 2) ^ ((m & 7) << 4));
    }

    float cr[4] = {};
#pragma unroll
    for (int r = 0; r < 4; ++r) {
        *(unsigned short*)((char*)&HA[0][0][0] + wo[r]) = 0;
        *(unsigned short*)((char*)&HL[0][0][0] + wo[r]) = 0;
    }
    __syncthreads();

    if (role == 0) {
        // ================= role0: layer0, fused x-GEMM, h0 export ========
        bf16x8 wi_h[4], wi_l[4];
        float nb[4];
#pragma unroll
        for (int t = 0; t < 4; ++t) {
            const float sc = (t == 2) ? L2E2 : L2E;
            int n = (t * 8 + wv) * 16 + ml;
            const float* s = w_ih0 + (size_t)n * NI + quad * 8;
            float4 v0 = *(const float4*)s;
            float4 v1 = *(const float4*)(s + 4);
            uint4 H, L;
            split2(v0.x * sc, v0.y * sc, H.x, L.x); split2(v0.z * sc, v0.w * sc, H.y, L.y);
            split2(v1.x * sc, v1.y * sc, H.z, L.z); split2(v1.z * sc, v1.w * sc, H.w, L.w);
            wi_h[t] = u4bf(H);
            wi_l[t] = u4bf(L);
            int nn = t * 128 + j;
            nb[t] = -(b_ih0[nn] + b_hh0[nn]) * sc;
        }

        const int erow = tid >> 5;
        const int eoff = erow * 256 + (((tid & 31) * 8) ^ ((erow & 7) << 4));

        const float* xrow = x + (size_t)(p * 16 + ml) * NT * NI + quad * 8;
        auto xload = [&](float4& a, float4& b, int T) __attribute__((always_inline)) {
            const float* sp = xrow + (size_t)T * NI;
            a = *(const float4*)sp;
            b = *(const float4*)(sp + 4);
        };

        auto exp0 = [&](int T, int BUF) __attribute__((always_inline)) {
            // export h_{T-1} (resident in HA/HL[BUF]) -> linear [m][j] planes
            u64 vh = *(const u64*)((const char*)&HA[BUF][0][0] + eoff);
            u64 vl = *(const u64*)((const char*)&HL[BUF][0][0] + eoff);
            ast64(h0pl + (((size_t)(T - 1) * 2 + 0) * 32 + p) * 512 + tid, vh);
            ast64(h0pl + (((size_t)(T - 1) * 2 + 1) * 32 + p) * 512 + tid, vl);
        };

        auto step0 = [&](int TL, int BUF, float4 x0, float4 x1)
            __attribute__((always_inline)) {
            const char* hb = (const char*)&HA[BUF][0][0];
            const char* lb = (const char*)&HL[BUF][0][0];
            char* hbn = (char*)&HA[BUF ^ 1][0][0];
            char* lbn = (char*)&HL[BUF ^ 1][0][0];
            uint4 XH, XL;
            split2(x0.x, x0.y, XH.x, XL.x); split2(x0.z, x0.w, XH.y, XL.y);
            split2(x1.x, x1.y, XH.z, XL.z); split2(x1.z, x1.w, XH.w, XL.w);
            bf16x8 xh = u4bf(XH), xl = u4bf(XL);
            f32x4 P[4] = {}, Q[4] = {};
#pragma unroll
            for (int t = 0; t < 4; ++t) {
                MFMA16(P[t], xh, wi_h[t]);
                MFMA16(Q[t], xl, wi_h[t]);
                MFMA16(Q[t], xh, wi_l[t]);
            }
#pragma unroll
            for (int q = 0; q < 4; ++q) {
                bf16x8 ah = *(const bf16x8*)(hb + ro[q]);
                bf16x8 al = *(const bf16x8*)(lb + ro[q]);
#pragma unroll
                for (int t = 0; t < 4; ++t) {
                    MFMA16(P[t], ah, wh[t][q]);
                    MFMA16(Q[t], al, wh[t][q]);
                    if (q & 1) { MFMA16(P[t], ah, wl[t][q]); }
                    else       { MFMA16(Q[t], ah, wl[t][q]); }
                }
            }
#pragma unroll
            for (int r = 0; r < 4; ++r) {
                float mi = nb[0] - P[0][r] - Q[0][r];
                float mf = nb[1] - P[1][r] - Q[1][r];
                float mg = nb[2] - P[2][r] - Q[2][r];
                float mo = nb[3] - P[3][r] - Q[3][r];
                float hn = activ(mi, mf, mg, mo, cr[r]);
                unsigned short hi = f2bf_rne(hn);
                float res = hn - __uint_as_float((unsigned)hi << 16);
                unsigned short lo = f2bf_rne(res);
                *(unsigned short*)(hbn + wo[r]) = hi;
                *(unsigned short*)(lbn + wo[r]) = lo;
            }
        };

        float4 xa0, xa1, xb0, xb1;
        xload(xa0, xa1, 0);
        for (int t = 0; t < 256; t += 2) {
            if (t > 0) {
                exp0(t, 0);
                if ((t & 3) == 0) {
                    vm_drain();
                    __syncthreads();
                    if (tid == 0) astu(&ctr0[p * 16], (unsigned)t);
                }
            }
            xload(xb0, xb1, t + 1);
            step0(t, 0, xa0, xa1);
            lds_barrier();
            exp0(t + 1, 1);
            xload(xa0, xa1, t + 2 > 255 ? 255 : t + 2);
            step0(t + 1, 1, xb0, xb1);
            lds_barrier();
        }
        exp0(256, 0);                      // h_255
        vm_drain();
        __syncthreads();
        if (tid == 0) astu(&ctr0[p * 16], 256u);
        return;
    }

    // ================= role1: layer1, BOTH matmuls, fc head ==============
    {
        // W_ih1 (scaled) hi+lo in registers (AGPR-backed like wh/wl)
        bf16x8 vih[4][4], vil[4][4];
        float nb[4];
#pragma unroll
        for (int t = 0; t < 4; ++t) {
            const float sc = (t == 2) ? L2E2 : L2E;
#pragma unroll
            for (int q = 0; q < 4; ++q) {
                int n = (t * 8 + wv) * 16 + ml;
                const float* s = w_ih1 + (size_t)n * NH + q * 32 + quad * 8;
                float4 v0 = *(const float4*)s;
                float4 v1 = *(const float4*)(s + 4);
                uint4 H, L;
                split2(v0.x * sc, v0.y * sc, H.x, L.x); split2(v0.z * sc, v0.w * sc, H.y, L.y);
                split2(v1.x * sc, v1.y * sc, H.z, L.z); split2(v1.z * sc, v1.w * sc, H.w, L.w);
                vih[t][q] = u4bf(H);
                vil[t][q] = u4bf(L);
            }
            int nn = t * 128 + j;
            nb[t] = -(b_ih1[nn] + b_hh1[nn]) * sc;
        }

        // h0 staging: thread tid handles plane u64 idx=tid -> row m=tid>>5,
        // cols 4*(tid&31); LDS dest swizzled like HA/HL so ro[q] reads work.
        const int gm = tid >> 5;
        const int go = gm * 256 + (((tid & 31) * 8) ^ ((gm & 7) << 4));

        auto pld = [&](u64& a, u64& b, int T) __attribute__((always_inline)) {
            int Tc = T < 255 ? T : 255;
            a = ald64(h0pl + (((size_t)Tc * 2 + 0) * 32 + p) * 512 + tid);
            b = ald64(h0pl + (((size_t)Tc * 2 + 1) * 32 + p) * 512 + tid);
        };
        auto gwr = [&](u64 a, u64 b, int BUF) __attribute__((always_inline)) {
            *(u64*)((char*)&GH[BUF][0][0] + go) = a;
            *(u64*)((char*)&GL[BUF][0][0] + go) = b;
        };
        auto wwait = [&](int need) __attribute__((always_inline)) {
            if (tid == 0) {
                while ((int)aldu(&ctr0[p * 16]) < need)
                    __builtin_amdgcn_s_sleep(4);
            }
            __syncthreads();
            asm volatile("" ::: "memory");
        };

        auto step1 = [&](int TL, int BUF) __attribute__((always_inline)) {
            const char* hb = (const char*)&HA[BUF][0][0];
            const char* lb = (const char*)&HL[BUF][0][0];
            const char* gb = (const char*)&GH[BUF][0][0];
            const char* glb = (const char*)&GL[BUF][0][0];
            char* hbn = (char*)&HA[BUF ^ 1][0][0];
            char* lbn = (char*)&HL[BUF ^ 1][0][0];
            f32x4 P[4] = {}, Q[4] = {};
            // ih1 part: A = h0_t fragments from G tiles
#pragma unroll
            for (int q = 0; q < 4; ++q) {
                bf16x8 gh = *(const bf16x8*)(gb + ro[q]);
                bf16x8 gl = *(const bf16x8*)(glb + ro[q]);
#pragma unroll
                for (int t = 0; t < 4; ++t) {
                    MFMA16(P[t], gh, vih[t][q]);
                    MFMA16(Q[t], gl, vih[t][q]);
                    if (q & 1) { MFMA16(P[t], gh, vil[t][q]); }
                    else       { MFMA16(Q[t], gh, vil[t][q]); }
                }
            }
            // hh1 part: A = h1_{t-1} fragments from H tiles
#pragma unroll
            for (int q = 0; q < 4; ++q) {
                bf16x8 ah = *(const bf16x8*)(hb + ro[q]);
                bf16x8 al = *(const bf16x8*)(lb + ro[q]);
#pragma unroll
                for (int t = 0; t < 4; ++t) {
                    MFMA16(P[t], ah, wh[t][q]);
                    MFMA16(Q[t], al, wh[t][q]);
                    if (q & 1) { MFMA16(P[t], ah, wl[t][q]); }
                    else       { MFMA16(Q[t], ah, wl[t][q]); }
                }
            }
#pragma unroll
            for (int r = 0; r < 4; ++r) {
                float mi = nb[0] - P[0][r] - Q[0][r];
                float mf = nb[1] - P[1][r] - Q[1][r];
                float mg = nb[2] - P[2][r] - Q[2][r];
                float mo = nb[3] - P[3][r] - Q[3][r];
                float hn = activ(mi, mf, mg, mo, cr[r]);
                unsigned short hi = f2bf_rne(hn);
                float res = hn - __uint_as_float((unsigned)hi << 16);
                unsigned short lo = f2bf_rne(res);
                *(unsigned short*)(hbn + wo[r]) = hi;
                *(unsigned short*)(lbn + wo[r]) = lo;
                if (TL == 255)
                    h1s[(size_t)(p * 16 + quad * 4 + r) * NH + j] = hn;
            }
        };

        // prologue: h0_0 staged to G[0]; h0_1 in regs
        wwait(4);
        u64 a0, a1, b0, b1;
        pld(a0, a1, 0);
        gwr(a0, a1, 0);
        pld(b0, b1, 1);
        __syncthreads();

        for (int t = 0; t < 256; t += 2) {
            // windows: at t=4w+2, ensure ctr0 >= 4w+8 before touching h0_{4w+4}
            if ((t & 3) == 2) wwait(t + 6 > 256 ? 256 : t + 6);
            gwr(b0, b1, 1);             // h0_{t+1} -> G[1] (read next step)
            pld(a0, a1, t + 2);         // issue h0_{t+2} loads (used step t+1)
            step1(t, 0);                // reads H[0],G[0]; writes H[1]
            lds_barrier();
            gwr(a0, a1, 0);             // h0_{t+2} -> G[0]
            pld(b0, b1, t + 3);
            step1(t + 1, 1);            // reads H[1],G[1]; writes H[0]
            lds_barrier();
        }

        // fc head: out[b] = fc2 . relu(fc1 @ h1_last + b1) + b2
        vm_drain();
        __syncthreads();
        const int g = tid >> 5;
        const int l = tid & 31;
        const float4* h4 = (const float4*)(h1s + (size_t)(p * 16 + g) * NH);
        const float4* w0 = (const float4*)(fc1w + (size_t)l * NH);
        const float4* w1 = (const float4*)(fc1w + (size_t)(l + 32) * NH);
        float a0f = fc1b[l], a1f = fc1b[l + 32];
#pragma unroll
        for (int q = 0; q < 32; ++q) {
            float4 h = h4[q], u = w0[q], v = w1[q];
            a0f += u.x * h.x + u.y * h.y + u.z * h.z + u.w * h.w;
            a1f += v.x * h.x + v.y * h.y + v.z * h.z + v.w * h.w;
        }
        float pv = fc2w[l] * fmaxf(a0f, 0.f) + fc2w[l + 32] * fmaxf(a1f, 0.f);
#pragma unroll
        for (int off = 16; off > 0; off >>= 1) pv += __shfl_down(pv, off, 32);
        if (l == 0) out[p * 16 + g] = pv + fc2b[0];
    }
}

extern "C" void kernel_launch(void* const* d_in, const int* in_sizes, int n_in,
                              void* d_out, int out_size, void* d_ws, size_t ws_size,
                              hipStream_t stream)
{
    const float* x     = (const float*)d_in[0];
    const float* w_ih0 = (const float*)d_in[1];
    const float* w_hh0 = (const float*)d_in[2];
    const float* b_ih0 = (const float*)d_in[3];
    const float* b_hh0 = (const float*)d_in[4];
    const float* w_ih1 = (const float*)d_in[5];
    const float* w_hh1 = (const float*)d_in[6];
    const float* b_ih1 = (const float*)d_in[7];
    const float* b_hh1 = (const float*)d_in[8];
    const float* fc1w  = (const float*)d_in[9];
    const float* fc1b  = (const float*)d_in[10];
    const float* fc2w  = (const float*)d_in[11];
    const float* fc2b  = (const float*)d_in[12];
    float* out = (float*)d_out;
    float* ws  = (float*)d_ws;

    // ws (floats): h0 planes 256*2*32*512 u64 = 16.78M floats (67 MB)
    //            | h1s 64K | ctr0 512 u32  -> ~67.4 MB total
    size_t o_h0  = 0;
    size_t o_h1s = o_h0 + (size_t)256 * 2 * 32 * 1024;
    size_t o_ctr = o_h1s + (size_t)NB * NH;

    u64*      h0pl = (u64*)(ws + o_h0);
    float*    h1sp = ws + o_h1s;
    unsigned* ctr0 = (unsigned*)(ws + o_ctr);

    hipMemsetAsync(ctr0, 0, 32 * 16 * sizeof(unsigned), stream);

    void* args[] = {
        (void*)&x,
        (void*)&w_hh0, (void*)&w_hh1,
        (void*)&w_ih0, (void*)&b_ih0, (void*)&b_hh0,
        (void*)&w_ih1, (void*)&b_ih1, (void*)&b_hh1,
        (void*)&fc1w, (void*)&fc1b, (void*)&fc2w, (void*)&fc2b,
        (void*)&h0pl, (void*)&h1sp, (void*)&out, (void*)&ctr0,
    };
    hipLaunchCooperativeKernel((const void*)fused, dim3(64), dim3(512),
                               args, 0, stream);
}

// Round 7
// 729.122 us; speedup vs baseline: 3.8575x; 3.8575x over previous
//
#include <hip/hip_runtime.h>

#define NB 512
#define NT 256
#define NI 32
#define NH 128
#define NG 512
#define WIN 4            // steps per xg1 window
#define NWIN 64          // NT/WIN
#define RING 16          // xg1 ring slots (windows)
#define NWRK 192         // gemm worker blocks

#define L2E  1.4426950408889634f
#define L2E2 2.8853900817779268f

typedef __attribute__((ext_vector_type(8))) short bf16x8;
typedef __attribute__((ext_vector_type(4))) float f32x4;
typedef unsigned long long u64;

__device__ __forceinline__ unsigned short f2bf_rne(float f) {
    unsigned u = __float_as_uint(f);
    return (unsigned short)((u + 0x7FFFu + ((u >> 16) & 1u)) >> 16);
}
__device__ __forceinline__ void split2(float a, float b, unsigned& hi, unsigned& lo) {
    unsigned short ha = f2bf_rne(a), hb = f2bf_rne(b);
    float ra = a - __uint_as_float((unsigned)ha << 16);
    float rb = b - __uint_as_float((unsigned)hb << 16);
    hi = (unsigned)ha | ((unsigned)hb << 16);
    lo = (unsigned)f2bf_rne(ra) | ((unsigned)f2bf_rne(rb) << 16);
}
__device__ __forceinline__ bf16x8 u4bf(uint4 u) {
    union { uint4 u; bf16x8 v; } c; c.u = u; return c.v;
}
#define MFMA16(accv, av, bv) \
    accv = __builtin_amdgcn_mfma_f32_16x16x32_bf16(av, bv, accv, 0, 0, 0)

__device__ __forceinline__ void lds_barrier() {
    asm volatile("s_waitcnt lgkmcnt(0)\n\ts_barrier" ::: "memory");
}
__device__ __forceinline__ void vm_drain() {
    asm volatile("s_waitcnt vmcnt(0)" ::: "memory");
}

// AGENT-scope relaxed atomics: each access goes to the coherence point (LLC),
// cross-XCD safe with NO fences and NO L2 writebacks.
__device__ __forceinline__ u64 ald64(const u64* p) {
    return __hip_atomic_load(p, __ATOMIC_RELAXED, __HIP_MEMORY_SCOPE_AGENT);
}
__device__ __forceinline__ void ast64(u64* p, u64 v) {
    __hip_atomic_store(p, v, __ATOMIC_RELAXED, __HIP_MEMORY_SCOPE_AGENT);
}
__device__ __forceinline__ unsigned aldu(const unsigned* p) {
    return __hip_atomic_load(p, __ATOMIC_RELAXED, __HIP_MEMORY_SCOPE_AGENT);
}
__device__ __forceinline__ void astu(unsigned* p, unsigned v) {
    __hip_atomic_store(p, v, __ATOMIC_RELAXED, __HIP_MEMORY_SCOPE_AGENT);
}

// fused activation: inputs m_* = -(log2e-scaled preact); updates c, returns h
__device__ __forceinline__ float activ(float mi, float mf, float mg, float mo,
                                       float& c) {
    float ei = exp2f(mi), ef = exp2f(mf), eg = exp2f(mg), eo = exp2f(mo);
    float rf  = __builtin_amdgcn_rcpf(1.0f + ef);
    float rig = __builtin_amdgcn_rcpf((1.0f + ei) * (1.0f + eg));
    float cn  = c * rf + (1.0f - eg) * rig;
    c = cn;
    float ec = exp2f(cn * -L2E2);
    float rh = __builtin_amdgcn_rcpf((1.0f + eo) * (1.0f + ec));
    return (1.0f - ec) * rh;
}

// ---------------------------------------------------------------------------
// R21 = R19 (proven 740us) + two targeted fixes from its counters:
//  1. role1 xg prefetch distance 1 -> 2 (4 reg buffers): R19's steady-state
//     step settled at the LLC round-trip (~2.4us) because each load had only
//     one step of cover. Depth 2 halves the exposed latency.
//  2. ring layout [tt][quad_m][n][r]: 16 consecutive lanes now read AND write
//     256B-contiguous runs (was 8B stores at 64B stride -> 590MB HBM writes
//     for 335MB logical, ~2x amplification).
// Structure unchanged: role0 (layer0+x-GEMM fused, h0 plane export) ->
// 192 slack-rich workers (xg1 = ih1 GEMM, window flags) -> role1 (layer1,
// ring consumer) ; all messaging via relaxed AGENT atomics at the LLC.
// ---------------------------------------------------------------------------
__global__ __launch_bounds__(512, 1)
void fused(const float* __restrict__ x,
           const float* __restrict__ w_hh0, const float* __restrict__ w_hh1,
           const float* __restrict__ w_ih0, const float* __restrict__ b_ih0,
           const float* __restrict__ b_hh0,
           const float* __restrict__ w_ih1, const float* __restrict__ b_ih1,
           const float* __restrict__ b_hh1,
           const float* __restrict__ fc1w, const float* __restrict__ fc1b,
           const float* __restrict__ fc2w, const float* __restrict__ fc2b,
           u64* __restrict__ h0pl,                 // [256][2][32][512] u64
           float* __restrict__ xgr,                // [RING][32][WIN][4][4][512][4]... see layout
           float* __restrict__ h1s, float* __restrict__ out,
           unsigned* __restrict__ ctr0, unsigned* __restrict__ flagW,
           unsigned* __restrict__ ctr1)
{
    __shared__ __align__(16) unsigned short HA[2][16][128];   // 8 KB
    __shared__ __align__(16) unsigned short HL[2][16][128];   // 8 KB

    const int bid  = blockIdx.x;
    const int tid  = threadIdx.x;
    const int wv   = tid >> 6;
    const int lane = tid & 63;
    const int quad = lane >> 4;
    const int ml   = lane & 15;

    // =====================================================================
    if (bid >= 64) {                       // ---------------- GEMM workers
        const int wk = bid - 64;
        for (int tile = wk; tile < 32 * NWIN; tile += NWRK) {
            const int w  = tile >> 5;
            const int pp = tile & 31;
            while (aldu(&ctr0[pp * 16]) < (unsigned)(4 * w + 4))
                __builtin_amdgcn_s_sleep(8);
            if (w >= RING)
                while (aldu(&ctr1[pp * 16]) < (unsigned)(w - (RING - 1)))
                    __builtin_amdgcn_s_sleep(8);
            asm volatile("" ::: "memory");

            bf16x8 A[4][4][2];             // [tt][q][plane]
#pragma unroll
            for (int tt = 0; tt < 4; ++tt)
#pragma unroll
                for (int q = 0; q < 4; ++q)
#pragma unroll
                    for (int pl = 0; pl < 2; ++pl) {
                        const u64* ap =
                            h0pl + (((size_t)(4 * w + tt) * 2 + pl) * 32 + pp) * 512
                                 + ml * 32 + q * 8 + quad * 2;
                        u64 a0 = ald64(ap), a1 = ald64(ap + 1);
                        uint4 U;
                        U.x = (unsigned)a0; U.y = (unsigned)(a0 >> 32);
                        U.z = (unsigned)a1; U.w = (unsigned)(a1 >> 32);
                        A[tt][q][pl] = u4bf(U);
                    }

            f32x4 acc[4][4] = {};
#pragma unroll
            for (int nt = 0; nt < 4; ++nt) {
                const float* bw = w_ih1
                    + (size_t)(wv * 64 + nt * 16 + ml) * NH + quad * 8;
                bf16x8 bh[4], bl[4];
#pragma unroll
                for (int q = 0; q < 4; ++q) {
                    float4 v0 = *(const float4*)(bw + q * 32);
                    float4 v1 = *(const float4*)(bw + q * 32 + 4);
                    uint4 H, L;
                    split2(v0.x, v0.y, H.x, L.x); split2(v0.z, v0.w, H.y, L.y);
                    split2(v1.x, v1.y, H.z, L.z); split2(v1.z, v1.w, H.w, L.w);
                    bh[q] = u4bf(H); bl[q] = u4bf(L);
                }
#pragma unroll
                for (int tt = 0; tt < 4; ++tt)
#pragma unroll
                    for (int q = 0; q < 4; ++q) {
                        MFMA16(acc[tt][nt], A[tt][q][0], bh[q]);
                        MFMA16(acc[tt][nt], A[tt][q][1], bh[q]);
                        MFMA16(acc[tt][nt], A[tt][q][0], bl[q]);
                    }
            }

            // ring store, coalesced layout: addr(tt,n,m) =
            //   tt*8192 + (m>>2)*2048 + (n>>7)*512 + (n&127)*4 + (m&3)
            // -> a lane's 4 regs (m = quad*4+r) are 16B contiguous; lanes
            //    ml adjacent -> n adjacent -> 256B contiguous per 16 lanes.
            const int slot = w & (RING - 1);
            float* cb = xgr + ((size_t)slot * 32 + pp) * WIN * 8192;
#pragma unroll
            for (int nt = 0; nt < 4; ++nt) {
                int n = wv * 64 + nt * 16 + ml;
                float s = ((n >> 7) == 2) ? L2E2 : L2E;
                float nbs = -(b_ih1[n] + b_hh1[n]) * s;
                int aoff = quad * 2048 + (n >> 7) * 512 + (n & 127) * 4;
#pragma unroll
                for (int tt = 0; tt < 4; ++tt) {
                    float* cp = cb + (size_t)tt * 8192 + aoff;
                    float v0 = fmaf(acc[tt][nt][0], -s, nbs);
                    float v1 = fmaf(acc[tt][nt][1], -s, nbs);
                    float v2 = fmaf(acc[tt][nt][2], -s, nbs);
                    float v3 = fmaf(acc[tt][nt][3], -s, nbs);
                    ast64((u64*)cp,
                          (u64)__float_as_uint(v0) |
                          ((u64)__float_as_uint(v1) << 32));
                    ast64((u64*)(cp + 2),
                          (u64)__float_as_uint(v2) |
                          ((u64)__float_as_uint(v3) << 32));
                }
            }
            vm_drain();
            __syncthreads();
            if (tid == 0) astu(&flagW[pp * 64 + w], 1u);
        }
        return;
    }

    // =====================================================================
    // recurrence roles
    const int role = bid >> 5;
    const int p    = bid & 31;
    const int j    = 16 * wv + ml;
    const float* wsrc = role ? w_hh1 : w_hh0;

    bf16x8 wh[4][4], wl[4][4];
#pragma unroll
    for (int t = 0; t < 4; ++t) {
        const float sc = (t == 2) ? L2E2 : L2E;
#pragma unroll
        for (int q = 0; q < 4; ++q) {
            int n = (t * 8 + wv) * 16 + ml;
            const float* s = wsrc + (size_t)n * NH + q * 32 + quad * 8;
            float4 v0 = *(const float4*)s;
            float4 v1 = *(const float4*)(s + 4);
            uint4 H, L;
            split2(v0.x * sc, v0.y * sc, H.x, L.x); split2(v0.z * sc, v0.w * sc, H.y, L.y);
            split2(v1.x * sc, v1.y * sc, H.z, L.z); split2(v1.z * sc, v1.w * sc, H.w, L.w);
            wh[t][q] = u4bf(H);
            wl[t][q] = u4bf(L);
        }
    }

    int ro[4];
#pragma unroll
    for (int q = 0; q < 4; ++q)
        ro[q] = ((ml * 256 + q * 64 + quad * 16) ^ ((ml & 7) << 4));
    int wo[4];
#pragma unroll
    for (int r = 0; r < 4; ++r) {
        int m = quad * 4 + r;
        wo[r] = ((m * 256 + j * 2) ^ ((m & 7) << 4));
    }

    float cr[4] = {};
#pragma unroll
    for (int r = 0; r < 4; ++r) {
        *(unsigned short*)((char*)&HA[0][0][0] + wo[r]) = 0;
        *(unsigned short*)((char*)&HL[0][0][0] + wo[r]) = 0;
    }
    __syncthreads();

    if (role == 0) {
        // ================= role0: layer0, fused x-GEMM, h0 export ========
        bf16x8 wi_h[4], wi_l[4];
        float nb[4];
#pragma unroll
        for (int t = 0; t < 4; ++t) {
            const float sc = (t == 2) ? L2E2 : L2E;
            int n = (t * 8 + wv) * 16 + ml;
            const float* s = w_ih0 + (size_t)n * NI + quad * 8;
            float4 v0 = *(const float4*)s;
            float4 v1 = *(const float4*)(s + 4);
            uint4 H, L;
            split2(v0.x * sc, v0.y * sc, H.x, L.x); split2(v0.z * sc, v0.w * sc, H.y, L.y);
            split2(v1.x * sc, v1.y * sc, H.z, L.z); split2(v1.z * sc, v1.w * sc, H.w, L.w);
            wi_h[t] = u4bf(H);
            wi_l[t] = u4bf(L);
            int nn = t * 128 + j;
            nb[t] = -(b_ih0[nn] + b_hh0[nn]) * sc;
        }

        const int erow = tid >> 5;
        const int eoff = erow * 256 + (((tid & 31) * 8) ^ ((erow & 7) << 4));

        const float* xrow = x + (size_t)(p * 16 + ml) * NT * NI + quad * 8;
        auto xload = [&](float4& a, float4& b, int T) __attribute__((always_inline)) {
            const float* sp = xrow + (size_t)T * NI;
            a = *(const float4*)sp;
            b = *(const float4*)(sp + 4);
        };

        auto exp0 = [&](int T, int BUF) __attribute__((always_inline)) {
            // export h_{T-1} (resident in HA/HL[BUF]) -> linear [m][j] planes
            u64 vh = *(const u64*)((const char*)&HA[BUF][0][0] + eoff);
            u64 vl = *(const u64*)((const char*)&HL[BUF][0][0] + eoff);
            ast64(h0pl + (((size_t)(T - 1) * 2 + 0) * 32 + p) * 512 + tid, vh);
            ast64(h0pl + (((size_t)(T - 1) * 2 + 1) * 32 + p) * 512 + tid, vl);
        };

        auto step0 = [&](int TL, int BUF, float4 x0, float4 x1)
            __attribute__((always_inline)) {
            const char* hb = (const char*)&HA[BUF][0][0];
            const char* lb = (const char*)&HL[BUF][0][0];
            char* hbn = (char*)&HA[BUF ^ 1][0][0];
            char* lbn = (char*)&HL[BUF ^ 1][0][0];
            uint4 XH, XL;
            split2(x0.x, x0.y, XH.x, XL.x); split2(x0.z, x0.w, XH.y, XL.y);
            split2(x1.x, x1.y, XH.z, XL.z); split2(x1.z, x1.w, XH.w, XL.w);
            bf16x8 xh = u4bf(XH), xl = u4bf(XL);
            f32x4 P[4] = {}, Q[4] = {};
#pragma unroll
            for (int t = 0; t < 4; ++t) {
                MFMA16(P[t], xh, wi_h[t]);
                MFMA16(Q[t], xl, wi_h[t]);
                MFMA16(Q[t], xh, wi_l[t]);
            }
#pragma unroll
            for (int q = 0; q < 4; ++q) {
                bf16x8 ah = *(const bf16x8*)(hb + ro[q]);
                bf16x8 al = *(const bf16x8*)(lb + ro[q]);
#pragma unroll
                for (int t = 0; t < 4; ++t) {
                    MFMA16(P[t], ah, wh[t][q]);
                    MFMA16(Q[t], al, wh[t][q]);
                    if (q & 1) { MFMA16(P[t], ah, wl[t][q]); }
                    else       { MFMA16(Q[t], ah, wl[t][q]); }
                }
            }
#pragma unroll
            for (int r = 0; r < 4; ++r) {
                float mi = nb[0] - P[0][r] - Q[0][r];
                float mf = nb[1] - P[1][r] - Q[1][r];
                float mg = nb[2] - P[2][r] - Q[2][r];
                float mo = nb[3] - P[3][r] - Q[3][r];
                float hn = activ(mi, mf, mg, mo, cr[r]);
                unsigned short hi = f2bf_rne(hn);
                float res = hn - __uint_as_float((unsigned)hi << 16);
                unsigned short lo = f2bf_rne(res);
                *(unsigned short*)(hbn + wo[r]) = hi;
                *(unsigned short*)(lbn + wo[r]) = lo;
            }
        };

        float4 xa0, xa1, xb0, xb1;
        xload(xa0, xa1, 0);
        for (int t = 0; t < 256; t += 2) {
            if (t > 0) {
                exp0(t, 0);
                if ((t & 3) == 0) {
                    vm_drain();
                    __syncthreads();
                    if (tid == 0) astu(&ctr0[p * 16], (unsigned)t);
                }
            }
            xload(xb0, xb1, t + 1);
            step0(t, 0, xa0, xa1);
            lds_barrier();
            exp0(t + 1, 1);
            xload(xa0, xa1, t + 2 > 255 ? 255 : t + 2);
            step0(t + 1, 1, xb0, xb1);
            lds_barrier();
        }
        exp0(256, 0);                      // h_255
        vm_drain();
        __syncthreads();
        if (tid == 0) astu(&ctr0[p * 16], 256u);
        return;
    }

    // ================= role1: layer1 recurrence + fc head ================
    {
        // coalesced ring read: value(n = tg*128+j, m = quad*4+r) at
        //   tt*8192 + quad*2048 + tg*512 + j*4 + r
        auto pxg = [&](float (&d)[4][4], int u) __attribute__((always_inline)) {
            int uc = u < 255 ? u : 255;
            int slot = (uc >> 2) & (RING - 1);
            int tt   = uc & 3;
            const float* b = xgr + (((size_t)slot * 32 + p) * WIN + tt) * 8192
                                 + quad * 2048 + j * 4;
#pragma unroll
            for (int tg = 0; tg < 4; ++tg) {
                u64 a0 = ald64((const u64*)(b + tg * 512));
                u64 a1 = ald64((const u64*)(b + tg * 512 + 2));
                d[tg][0] = __uint_as_float((unsigned)a0);
                d[tg][1] = __uint_as_float((unsigned)(a0 >> 32));
                d[tg][2] = __uint_as_float((unsigned)a1);
                d[tg][3] = __uint_as_float((unsigned)(a1 >> 32));
            }
        };

        auto step1 = [&](int TL, int BUF, const float (&xgv)[4][4])
            __attribute__((always_inline)) {
            const char* hb = (const char*)&HA[BUF][0][0];
            const char* lb = (const char*)&HL[BUF][0][0];
            char* hbn = (char*)&HA[BUF ^ 1][0][0];
            char* lbn = (char*)&HL[BUF ^ 1][0][0];
            f32x4 P[4] = {}, Q[4] = {};
#pragma unroll
            for (int q = 0; q < 4; ++q) {
                bf16x8 ah = *(const bf16x8*)(hb + ro[q]);
                bf16x8 al = *(const bf16x8*)(lb + ro[q]);
#pragma unroll
                for (int t = 0; t < 4; ++t) {
                    MFMA16(P[t], ah, wh[t][q]);
                    MFMA16(Q[t], al, wh[t][q]);
                    if (q & 1) { MFMA16(P[t], ah, wl[t][q]); }
                    else       { MFMA16(Q[t], ah, wl[t][q]); }
                }
            }
#pragma unroll
            for (int r = 0; r < 4; ++r) {
                float mi = xgv[0][r] - P[0][r] - Q[0][r];
                float mf = xgv[1][r] - P[1][r] - Q[1][r];
                float mg = xgv[2][r] - P[2][r] - Q[2][r];
                float mo = xgv[3][r] - P[3][r] - Q[3][r];
                float hn = activ(mi, mf, mg, mo, cr[r]);
                unsigned short hi = f2bf_rne(hn);
                float res = hn - __uint_as_float((unsigned)hi << 16);
                unsigned short lo = f2bf_rne(res);
                *(unsigned short*)(hbn + wo[r]) = hi;
                *(unsigned short*)(lbn + wo[r]) = lo;
                if (TL == 255)
                    h1s[(size_t)(p * 16 + quad * 4 + r) * NH + j] = hn;
            }
        };

        auto waitflag = [&](int wn) __attribute__((always_inline)) {
            if (tid == 0) {
                while (aldu(&flagW[p * 64 + wn]) == 0)
                    __builtin_amdgcn_s_sleep(2);
            }
            __syncthreads();
            asm volatile("" ::: "memory");
        };

        // prologue: window 0 ready, load steps 0 and 1 (distance-2 pipeline)
        waitflag(0);
        float xa[4][4], xb[4][4], xc[4][4], xd[4][4];
        pxg(xa, 0);
        pxg(xb, 1);

        for (int u = 0; u < 256; u += 4) {
            if (u > 0 && tid == 0) astu(&ctr1[p * 16], (unsigned)(u >> 2));
            pxg(xc, u + 2);                  // same window as u (u%4==0)
            step1(u, 0, xa);
            lds_barrier();
            pxg(xd, u + 3);
            step1(u + 1, 1, xb);
            lds_barrier();
            if (u + 4 < 256) waitflag((u + 4) >> 2);
            pxg(xa, u + 4);                  // next window (clamped at end)
            step1(u + 2, 0, xc);
            lds_barrier();
            pxg(xb, u + 5);
            step1(u + 3, 1, xd);
            lds_barrier();
        }

        // fc head: out[b] = fc2 . relu(fc1 @ h1_last + b1) + b2
        vm_drain();
        __syncthreads();
        const int g = tid >> 5;
        const int l = tid & 31;
        const float4* h4 = (const float4*)(h1s + (size_t)(p * 16 + g) * NH);
        const float4* w0 = (const float4*)(fc1w + (size_t)l * NH);
        const float4* w1 = (const float4*)(fc1w + (size_t)(l + 32) * NH);
        float a0 = fc1b[l], a1 = fc1b[l + 32];
#pragma unroll
        for (int q = 0; q < 32; ++q) {
            float4 h = h4[q], u = w0[q], v = w1[q];
            a0 += u.x * h.x + u.y * h.y + u.z * h.z + u.w * h.w;
            a1 += v.x * h.x + v.y * h.y + v.z * h.z + v.w * h.w;
        }
        float pv = fc2w[l] * fmaxf(a0, 0.f) + fc2w[l + 32] * fmaxf(a1, 0.f);
#pragma unroll
        for (int off = 16; off > 0; off >>= 1) pv += __shfl_down(pv, off, 32);
        if (l == 0) out[p * 16 + g] = pv + fc2b[0];
    }
}

extern "C" void kernel_launch(void* const* d_in, const int* in_sizes, int n_in,
                              void* d_out, int out_size, void* d_ws, size_t ws_size,
                              hipStream_t stream)
{
    const float* x     = (const float*)d_in[0];
    const float* w_ih0 = (const float*)d_in[1];
    const float* w_hh0 = (const float*)d_in[2];
    const float* b_ih0 = (const float*)d_in[3];
    const float* b_hh0 = (const float*)d_in[4];
    const float* w_ih1 = (const float*)d_in[5];
    const float* w_hh1 = (const float*)d_in[6];
    const float* b_ih1 = (const float*)d_in[7];
    const float* b_hh1 = (const float*)d_in[8];
    const float* fc1w  = (const float*)d_in[9];
    const float* fc1b  = (const float*)d_in[10];
    const float* fc2w  = (const float*)d_in[11];
    const float* fc2b  = (const float*)d_in[12];
    float* out = (float*)d_out;
    float* ws  = (float*)d_ws;

    // ws layout (floats):
    //  h0 planes: 256 t x 2 pl x 32 p x 4KB  = 16.78M floats (64 MB)
    //  xg ring  : RING x 32 p x WIN x 8192   = 16.78M floats (64 MB)
    //  h1s 64K | flags 3072 u32  -> total ~134.5 MB (<= proven 152 MB ws)
    size_t o_h0  = 0;
    size_t o_xgr = o_h0 + (size_t)256 * 2 * 32 * 1024;   // u64 count*2 floats
    size_t o_h1s = o_xgr + (size_t)RING * 32 * WIN * 8192;
    size_t o_flg = o_h1s + (size_t)NB * NH;

    u64*      h0pl = (u64*)(ws + o_h0);
    float*    xgr  = ws + o_xgr;
    float*    h1sp = ws + o_h1s;
    unsigned* ctr0 = (unsigned*)(ws + o_flg);
    unsigned* flagW = ctr0 + 32 * 16;
    unsigned* ctr1  = flagW + 32 * 64;

    hipMemsetAsync(ctr0, 0, (32 * 16 + 32 * 64 + 32 * 16) * sizeof(unsigned),
                   stream);

    void* args[] = {
        (void*)&x,
        (void*)&w_hh0, (void*)&w_hh1,
        (void*)&w_ih0, (void*)&b_ih0, (void*)&b_hh0,
        (void*)&w_ih1, (void*)&b_ih1, (void*)&b_hh1,
        (void*)&fc1w, (void*)&fc1b, (void*)&fc2w, (void*)&fc2b,
        (void*)&h0pl, (void*)&xgr, (void*)&h1sp, (void*)&out,
        (void*)&ctr0, (void*)&flagW, (void*)&ctr1,
    };
    hipLaunchCooperativeKernel((const void*)fused, dim3(256), dim3(512),
                               args, 0, stream);
}

// Round 8
// 725.035 us; speedup vs baseline: 3.8793x; 1.0056x over previous
//
#include <hip/hip_runtime.h>

#define NB 512
#define NT 256
#define NI 32
#define NH 128
#define NG 512
#define WIN 4            // steps per xg1 window
#define NWIN 64          // NT/WIN
#define RING 16          // xg1 ring slots (windows)
#define NWRK 192         // gemm worker blocks

#define L2E  1.4426950408889634f
#define L2E2 2.8853900817779268f

typedef __attribute__((ext_vector_type(8))) short bf16x8;
typedef __attribute__((ext_vector_type(4))) float f32x4;
typedef unsigned long long u64;

__device__ __forceinline__ unsigned short f2bf_rne(float f) {
    unsigned u = __float_as_uint(f);
    return (unsigned short)((u + 0x7FFFu + ((u >> 16) & 1u)) >> 16);
}
__device__ __forceinline__ void split2(float a, float b, unsigned& hi, unsigned& lo) {
    unsigned short ha = f2bf_rne(a), hb = f2bf_rne(b);
    float ra = a - __uint_as_float((unsigned)ha << 16);
    float rb = b - __uint_as_float((unsigned)hb << 16);
    hi = (unsigned)ha | ((unsigned)hb << 16);
    lo = (unsigned)f2bf_rne(ra) | ((unsigned)f2bf_rne(rb) << 16);
}
__device__ __forceinline__ bf16x8 u4bf(uint4 u) {
    union { uint4 u; bf16x8 v; } c; c.u = u; return c.v;
}
#define MFMA16(accv, av, bv) \
    accv = __builtin_amdgcn_mfma_f32_16x16x32_bf16(av, bv, accv, 0, 0, 0)

__device__ __forceinline__ void lds_barrier() {
    asm volatile("s_waitcnt lgkmcnt(0)\n\ts_barrier" ::: "memory");
}
__device__ __forceinline__ void vm_drain() {
    asm volatile("s_waitcnt vmcnt(0)" ::: "memory");
}
// Lazy release: only ops OLDER than the most recent 8 vmem ops must be done.
// role0 issues exactly 4 vmem ops/step (2 x-loads + 2 atomic exports), so
// this waits for stores >=2 steps old (>=3us) -> effectively free, yet
// everything covered by the lagged counter (t-4) is guaranteed visible.
__device__ __forceinline__ void vm_lazy8() {
    asm volatile("s_waitcnt vmcnt(8)" ::: "memory");
}

// AGENT-scope relaxed atomics: each access goes to the coherence point (LLC),
// cross-XCD safe with NO fences and NO L2 writebacks.
__device__ __forceinline__ u64 ald64(const u64* p) {
    return __hip_atomic_load(p, __ATOMIC_RELAXED, __HIP_MEMORY_SCOPE_AGENT);
}
__device__ __forceinline__ void ast64(u64* p, u64 v) {
    __hip_atomic_store(p, v, __ATOMIC_RELAXED, __HIP_MEMORY_SCOPE_AGENT);
}
__device__ __forceinline__ unsigned aldu(const unsigned* p) {
    return __hip_atomic_load(p, __ATOMIC_RELAXED, __HIP_MEMORY_SCOPE_AGENT);
}
__device__ __forceinline__ void astu(unsigned* p, unsigned v) {
    __hip_atomic_store(p, v, __ATOMIC_RELAXED, __HIP_MEMORY_SCOPE_AGENT);
}

// fused activation: inputs m_* = -(log2e-scaled preact); updates c, returns h
__device__ __forceinline__ float activ(float mi, float mf, float mg, float mo,
                                       float& c) {
    float ei = exp2f(mi), ef = exp2f(mf), eg = exp2f(mg), eo = exp2f(mo);
    float rf  = __builtin_amdgcn_rcpf(1.0f + ef);
    float rig = __builtin_amdgcn_rcpf((1.0f + ei) * (1.0f + eg));
    float cn  = c * rf + (1.0f - eg) * rig;
    c = cn;
    float ec = exp2f(cn * -L2E2);
    float rh = __builtin_amdgcn_rcpf((1.0f + eo) * (1.0f + ec));
    return (1.0f - ec) * rh;
}

// ---------------------------------------------------------------------------
// R22 = R21 + lazy-release export protocol in role0.
// Evidence chain: R17's identical role0 code ran 1.68us/step with no atomics;
// R19/R21 run it at 2.65us/step. The delta is the vmcnt(0) drain every 4
// steps blocking on just-issued LLC atomic store-acks. Fix: publish ctr0=t-4
// with s_waitcnt vmcnt(8) (waits only for ops >=2 steps old -> free). Workers
// and role1 absorb the +4-step lag (RING = 64 steps of slack).
// Structure unchanged: role0 (layer0 + x-GEMM fused, h0 plane export) ->
// 192 slack-rich workers (xg1 = ih1 GEMM, window flags) -> role1 (layer1,
// ring consumer); all messaging via relaxed AGENT atomics at the LLC.
// ---------------------------------------------------------------------------
__global__ __launch_bounds__(512, 1)
void fused(const float* __restrict__ x,
           const float* __restrict__ w_hh0, const float* __restrict__ w_hh1,
           const float* __restrict__ w_ih0, const float* __restrict__ b_ih0,
           const float* __restrict__ b_hh0,
           const float* __restrict__ w_ih1, const float* __restrict__ b_ih1,
           const float* __restrict__ b_hh1,
           const float* __restrict__ fc1w, const float* __restrict__ fc1b,
           const float* __restrict__ fc2w, const float* __restrict__ fc2b,
           u64* __restrict__ h0pl,                 // [256][2][32][512] u64
           float* __restrict__ xgr,                // ring, coalesced layout
           float* __restrict__ h1s, float* __restrict__ out,
           unsigned* __restrict__ ctr0, unsigned* __restrict__ flagW,
           unsigned* __restrict__ ctr1)
{
    __shared__ __align__(16) unsigned short HA[2][16][128];   // 8 KB
    __shared__ __align__(16) unsigned short HL[2][16][128];   // 8 KB

    const int bid  = blockIdx.x;
    const int tid  = threadIdx.x;
    const int wv   = tid >> 6;
    const int lane = tid & 63;
    const int quad = lane >> 4;
    const int ml   = lane & 15;

    // =====================================================================
    if (bid >= 64) {                       // ---------------- GEMM workers
        const int wk = bid - 64;
        for (int tile = wk; tile < 32 * NWIN; tile += NWRK) {
            const int w  = tile >> 5;
            const int pp = tile & 31;
            while (aldu(&ctr0[pp * 16]) < (unsigned)(4 * w + 4))
                __builtin_amdgcn_s_sleep(8);
            if (w >= RING)
                while (aldu(&ctr1[pp * 16]) < (unsigned)(w - (RING - 1)))
                    __builtin_amdgcn_s_sleep(8);
            asm volatile("" ::: "memory");

            bf16x8 A[4][4][2];             // [tt][q][plane]
#pragma unroll
            for (int tt = 0; tt < 4; ++tt)
#pragma unroll
                for (int q = 0; q < 4; ++q)
#pragma unroll
                    for (int pl = 0; pl < 2; ++pl) {
                        const u64* ap =
                            h0pl + (((size_t)(4 * w + tt) * 2 + pl) * 32 + pp) * 512
                                 + ml * 32 + q * 8 + quad * 2;
                        u64 a0 = ald64(ap), a1 = ald64(ap + 1);
                        uint4 U;
                        U.x = (unsigned)a0; U.y = (unsigned)(a0 >> 32);
                        U.z = (unsigned)a1; U.w = (unsigned)(a1 >> 32);
                        A[tt][q][pl] = u4bf(U);
                    }

            f32x4 acc[4][4] = {};
#pragma unroll
            for (int nt = 0; nt < 4; ++nt) {
                const float* bw = w_ih1
                    + (size_t)(wv * 64 + nt * 16 + ml) * NH + quad * 8;
                bf16x8 bh[4], bl[4];
#pragma unroll
                for (int q = 0; q < 4; ++q) {
                    float4 v0 = *(const float4*)(bw + q * 32);
                    float4 v1 = *(const float4*)(bw + q * 32 + 4);
                    uint4 H, L;
                    split2(v0.x, v0.y, H.x, L.x); split2(v0.z, v0.w, H.y, L.y);
                    split2(v1.x, v1.y, H.z, L.z); split2(v1.z, v1.w, H.w, L.w);
                    bh[q] = u4bf(H); bl[q] = u4bf(L);
                }
#pragma unroll
                for (int tt = 0; tt < 4; ++tt)
#pragma unroll
                    for (int q = 0; q < 4; ++q) {
                        MFMA16(acc[tt][nt], A[tt][q][0], bh[q]);
                        MFMA16(acc[tt][nt], A[tt][q][1], bh[q]);
                        MFMA16(acc[tt][nt], A[tt][q][0], bl[q]);
                    }
            }

            // ring store: addr(tt,n,m)= tt*8192 + (m>>2)*2048 + (n>>7)*512
            //                          + (n&127)*4 + (m&3)
            const int slot = w & (RING - 1);
            float* cb = xgr + ((size_t)slot * 32 + pp) * WIN * 8192;
#pragma unroll
            for (int nt = 0; nt < 4; ++nt) {
                int n = wv * 64 + nt * 16 + ml;
                float s = ((n >> 7) == 2) ? L2E2 : L2E;
                float nbs = -(b_ih1[n] + b_hh1[n]) * s;
                int aoff = quad * 2048 + (n >> 7) * 512 + (n & 127) * 4;
#pragma unroll
                for (int tt = 0; tt < 4; ++tt) {
                    float* cp = cb + (size_t)tt * 8192 + aoff;
                    float v0 = fmaf(acc[tt][nt][0], -s, nbs);
                    float v1 = fmaf(acc[tt][nt][1], -s, nbs);
                    float v2 = fmaf(acc[tt][nt][2], -s, nbs);
                    float v3 = fmaf(acc[tt][nt][3], -s, nbs);
                    ast64((u64*)cp,
                          (u64)__float_as_uint(v0) |
                          ((u64)__float_as_uint(v1) << 32));
                    ast64((u64*)(cp + 2),
                          (u64)__float_as_uint(v2) |
                          ((u64)__float_as_uint(v3) << 32));
                }
            }
            vm_drain();
            __syncthreads();
            if (tid == 0) astu(&flagW[pp * 64 + w], 1u);
        }
        return;
    }

    // =====================================================================
    // recurrence roles
    const int role = bid >> 5;
    const int p    = bid & 31;
    const int j    = 16 * wv + ml;
    const float* wsrc = role ? w_hh1 : w_hh0;

    bf16x8 wh[4][4], wl[4][4];
#pragma unroll
    for (int t = 0; t < 4; ++t) {
        const float sc = (t == 2) ? L2E2 : L2E;
#pragma unroll
        for (int q = 0; q < 4; ++q) {
            int n = (t * 8 + wv) * 16 + ml;
            const float* s = wsrc + (size_t)n * NH + q * 32 + quad * 8;
            float4 v0 = *(const float4*)s;
            float4 v1 = *(const float4*)(s + 4);
            uint4 H, L;
            split2(v0.x * sc, v0.y * sc, H.x, L.x); split2(v0.z * sc, v0.w * sc, H.y, L.y);
            split2(v1.x * sc, v1.y * sc, H.z, L.z); split2(v1.z * sc, v1.w * sc, H.w, L.w);
            wh[t][q] = u4bf(H);
            wl[t][q] = u4bf(L);
        }
    }

    int ro[4];
#pragma unroll
    for (int q = 0; q < 4; ++q)
        ro[q] = ((ml * 256 + q * 64 + quad * 16) ^ ((ml & 7) << 4));
    int wo[4];
#pragma unroll
    for (int r = 0; r < 4; ++r) {
        int m = quad * 4 + r;
        wo[r] = ((m * 256 + j * 2) ^ ((m & 7) << 4));
    }

    float cr[4] = {};
#pragma unroll
    for (int r = 0; r < 4; ++r) {
        *(unsigned short*)((char*)&HA[0][0][0] + wo[r]) = 0;
        *(unsigned short*)((char*)&HL[0][0][0] + wo[r]) = 0;
    }
    __syncthreads();

    if (role == 0) {
        // ================= role0: layer0, fused x-GEMM, h0 export ========
        bf16x8 wi_h[4], wi_l[4];
        float nb[4];
#pragma unroll
        for (int t = 0; t < 4; ++t) {
            const float sc = (t == 2) ? L2E2 : L2E;
            int n = (t * 8 + wv) * 16 + ml;
            const float* s = w_ih0 + (size_t)n * NI + quad * 8;
            float4 v0 = *(const float4*)s;
            float4 v1 = *(const float4*)(s + 4);
            uint4 H, L;
            split2(v0.x * sc, v0.y * sc, H.x, L.x); split2(v0.z * sc, v0.w * sc, H.y, L.y);
            split2(v1.x * sc, v1.y * sc, H.z, L.z); split2(v1.z * sc, v1.w * sc, H.w, L.w);
            wi_h[t] = u4bf(H);
            wi_l[t] = u4bf(L);
            int nn = t * 128 + j;
            nb[t] = -(b_ih0[nn] + b_hh0[nn]) * sc;
        }

        const int erow = tid >> 5;
        const int eoff = erow * 256 + (((tid & 31) * 8) ^ ((erow & 7) << 4));

        const float* xrow = x + (size_t)(p * 16 + ml) * NT * NI + quad * 8;
        auto xload = [&](float4& a, float4& b, int T) __attribute__((always_inline)) {
            const float* sp = xrow + (size_t)T * NI;
            a = *(const float4*)sp;
            b = *(const float4*)(sp + 4);
        };

        auto exp0 = [&](int T, int BUF) __attribute__((always_inline)) {
            // export h_{T-1} (resident in HA/HL[BUF]) -> linear [m][j] planes
            u64 vh = *(const u64*)((const char*)&HA[BUF][0][0] + eoff);
            u64 vl = *(const u64*)((const char*)&HL[BUF][0][0] + eoff);
            ast64(h0pl + (((size_t)(T - 1) * 2 + 0) * 32 + p) * 512 + tid, vh);
            ast64(h0pl + (((size_t)(T - 1) * 2 + 1) * 32 + p) * 512 + tid, vl);
        };

        auto step0 = [&](int TL, int BUF, float4 x0, float4 x1)
            __attribute__((always_inline)) {
            const char* hb = (const char*)&HA[BUF][0][0];
            const char* lb = (const char*)&HL[BUF][0][0];
            char* hbn = (char*)&HA[BUF ^ 1][0][0];
            char* lbn = (char*)&HL[BUF ^ 1][0][0];
            uint4 XH, XL;
            split2(x0.x, x0.y, XH.x, XL.x); split2(x0.z, x0.w, XH.y, XL.y);
            split2(x1.x, x1.y, XH.z, XL.z); split2(x1.z, x1.w, XH.w, XL.w);
            bf16x8 xh = u4bf(XH), xl = u4bf(XL);
            f32x4 P[4] = {}, Q[4] = {};
#pragma unroll
            for (int t = 0; t < 4; ++t) {
                MFMA16(P[t], xh, wi_h[t]);
                MFMA16(Q[t], xl, wi_h[t]);
                MFMA16(Q[t], xh, wi_l[t]);
            }
#pragma unroll
            for (int q = 0; q < 4; ++q) {
                bf16x8 ah = *(const bf16x8*)(hb + ro[q]);
                bf16x8 al = *(const bf16x8*)(lb + ro[q]);
#pragma unroll
                for (int t = 0; t < 4; ++t) {
                    MFMA16(P[t], ah, wh[t][q]);
                    MFMA16(Q[t], al, wh[t][q]);
                    if (q & 1) { MFMA16(P[t], ah, wl[t][q]); }
                    else       { MFMA16(Q[t], ah, wl[t][q]); }
                }
            }
#pragma unroll
            for (int r = 0; r < 4; ++r) {
                float mi = nb[0] - P[0][r] - Q[0][r];
                float mf = nb[1] - P[1][r] - Q[1][r];
                float mg = nb[2] - P[2][r] - Q[2][r];
                float mo = nb[3] - P[3][r] - Q[3][r];
                float hn = activ(mi, mf, mg, mo, cr[r]);
                unsigned short hi = f2bf_rne(hn);
                float res = hn - __uint_as_float((unsigned)hi << 16);
                unsigned short lo = f2bf_rne(res);
                *(unsigned short*)(hbn + wo[r]) = hi;
                *(unsigned short*)(lbn + wo[r]) = lo;
            }
        };

        float4 xa0, xa1, xb0, xb1;
        xload(xa0, xa1, 0);
        for (int t = 0; t < 256; t += 2) {
            if (t > 0) {
                exp0(t, 0);
                if ((t & 3) == 0) {
                    vm_lazy8();            // waits only for ops >=2 steps old
                    __syncthreads();
                    if (tid == 0 && t >= 8)
                        astu(&ctr0[p * 16], (unsigned)(t - 4));  // lagged publish
                }
            }
            xload(xb0, xb1, t + 1);
            step0(t, 0, xa0, xa1);
            lds_barrier();
            exp0(t + 1, 1);
            xload(xa0, xa1, t + 2 > 255 ? 255 : t + 2);
            step0(t + 1, 1, xb0, xb1);
            lds_barrier();
        }
        exp0(256, 0);                      // h_255
        vm_drain();
        __syncthreads();
        if (tid == 0) astu(&ctr0[p * 16], 256u);
        return;
    }

    // ================= role1: layer1 recurrence + fc head ================
    {
        // coalesced ring read: value(n = tg*128+j, m = quad*4+r) at
        //   tt*8192 + quad*2048 + tg*512 + j*4 + r
        auto pxg = [&](float (&d)[4][4], int u) __attribute__((always_inline)) {
            int uc = u < 255 ? u : 255;
            int slot = (uc >> 2) & (RING - 1);
            int tt   = uc & 3;
            const float* b = xgr + (((size_t)slot * 32 + p) * WIN + tt) * 8192
                                 + quad * 2048 + j * 4;
#pragma unroll
            for (int tg = 0; tg < 4; ++tg) {
                u64 a0 = ald64((const u64*)(b + tg * 512));
                u64 a1 = ald64((const u64*)(b + tg * 512 + 2));
                d[tg][0] = __uint_as_float((unsigned)a0);
                d[tg][1] = __uint_as_float((unsigned)(a0 >> 32));
                d[tg][2] = __uint_as_float((unsigned)a1);
                d[tg][3] = __uint_as_float((unsigned)(a1 >> 32));
            }
        };

        auto step1 = [&](int TL, int BUF, const float (&xgv)[4][4])
            __attribute__((always_inline)) {
            const char* hb = (const char*)&HA[BUF][0][0];
            const char* lb = (const char*)&HL[BUF][0][0];
            char* hbn = (char*)&HA[BUF ^ 1][0][0];
            char* lbn = (char*)&HL[BUF ^ 1][0][0];
            f32x4 P[4] = {}, Q[4] = {};
#pragma unroll
            for (int q = 0; q < 4; ++q) {
                bf16x8 ah = *(const bf16x8*)(hb + ro[q]);
                bf16x8 al = *(const bf16x8*)(lb + ro[q]);
#pragma unroll
                for (int t = 0; t < 4; ++t) {
                    MFMA16(P[t], ah, wh[t][q]);
                    MFMA16(Q[t], al, wh[t][q]);
                    if (q & 1) { MFMA16(P[t], ah, wl[t][q]); }
                    else       { MFMA16(Q[t], ah, wl[t][q]); }
                }
            }
#pragma unroll
            for (int r = 0; r < 4; ++r) {
                float mi = xgv[0][r] - P[0][r] - Q[0][r];
                float mf = xgv[1][r] - P[1][r] - Q[1][r];
                float mg = xgv[2][r] - P[2][r] - Q[2][r];
                float mo = xgv[3][r] - P[3][r] - Q[3][r];
                float hn = activ(mi, mf, mg, mo, cr[r]);
                unsigned short hi = f2bf_rne(hn);
                float res = hn - __uint_as_float((unsigned)hi << 16);
                unsigned short lo = f2bf_rne(res);
                *(unsigned short*)(hbn + wo[r]) = hi;
                *(unsigned short*)(lbn + wo[r]) = lo;
                if (TL == 255)
                    h1s[(size_t)(p * 16 + quad * 4 + r) * NH + j] = hn;
            }
        };

        auto waitflag = [&](int wn) __attribute__((always_inline)) {
            if (tid == 0) {
                while (aldu(&flagW[p * 64 + wn]) == 0)
                    __builtin_amdgcn_s_sleep(2);
            }
            __syncthreads();
            asm volatile("" ::: "memory");
        };

        // prologue: window 0 ready, load steps 0 and 1 (distance-2 pipeline)
        waitflag(0);
        float xa[4][4], xb[4][4], xc[4][4], xd[4][4];
        pxg(xa, 0);
        pxg(xb, 1);

        for (int u = 0; u < 256; u += 4) {
            if (u > 0 && tid == 0) astu(&ctr1[p * 16], (unsigned)(u >> 2));
            pxg(xc, u + 2);                  // same window as u (u%4==0)
            step1(u, 0, xa);
            lds_barrier();
            pxg(xd, u + 3);
            step1(u + 1, 1, xb);
            lds_barrier();
            if (u + 4 < 256) waitflag((u + 4) >> 2);
            pxg(xa, u + 4);                  // next window (clamped at end)
            step1(u + 2, 0, xc);
            lds_barrier();
            pxg(xb, u + 5);
            step1(u + 3, 1, xd);
            lds_barrier();
        }

        // fc head: out[b] = fc2 . relu(fc1 @ h1_last + b1) + b2
        vm_drain();
        __syncthreads();
        const int g = tid >> 5;
        const int l = tid & 31;
        const float4* h4 = (const float4*)(h1s + (size_t)(p * 16 + g) * NH);
        const float4* w0 = (const float4*)(fc1w + (size_t)l * NH);
        const float4* w1 = (const float4*)(fc1w + (size_t)(l + 32) * NH);
        float a0 = fc1b[l], a1 = fc1b[l + 32];
#pragma unroll
        for (int q = 0; q < 32; ++q) {
            float4 h = h4[q], u = w0[q], v = w1[q];
            a0 += u.x * h.x + u.y * h.y + u.z * h.z + u.w * h.w;
            a1 += v.x * h.x + v.y * h.y + v.z * h.z + v.w * h.w;
        }
        float pv = fc2w[l] * fmaxf(a0, 0.f) + fc2w[l + 32] * fmaxf(a1, 0.f);
#pragma unroll
        for (int off = 16; off > 0; off >>= 1) pv += __shfl_down(pv, off, 32);
        if (l == 0) out[p * 16 + g] = pv + fc2b[0];
    }
}

extern "C" void kernel_launch(void* const* d_in, const int* in_sizes, int n_in,
                              void* d_out, int out_size, void* d_ws, size_t ws_size,
                              hipStream_t stream)
{
    const float* x     = (const float*)d_in[0];
    const float* w_ih0 = (const float*)d_in[1];
    const float* w_hh0 = (const float*)d_in[2];
    const float* b_ih0 = (const float*)d_in[3];
    const float* b_hh0 = (const float*)d_in[4];
    const float* w_ih1 = (const float*)d_in[5];
    const float* w_hh1 = (const float*)d_in[6];
    const float* b_ih1 = (const float*)d_in[7];
    const float* b_hh1 = (const float*)d_in[8];
    const float* fc1w  = (const float*)d_in[9];
    const float* fc1b  = (const float*)d_in[10];
    const float* fc2w  = (const float*)d_in[11];
    const float* fc2b  = (const float*)d_in[12];
    float* out = (float*)d_out;
    float* ws  = (float*)d_ws;

    // ws layout (floats):
    //  h0 planes: 256 t x 2 pl x 32 p x 4KB  = 16.78M floats (64 MB)
    //  xg ring  : RING x 32 p x WIN x 8192   = 16.78M floats (64 MB)
    //  h1s 64K | flags 3072 u32  -> total ~134.5 MB (<= proven 152 MB ws)
    size_t o_h0  = 0;
    size_t o_xgr = o_h0 + (size_t)256 * 2 * 32 * 1024;   // u64 count*2 floats
    size_t o_h1s = o_xgr + (size_t)RING * 32 * WIN * 8192;
    size_t o_flg = o_h1s + (size_t)NB * NH;

    u64*      h0pl = (u64*)(ws + o_h0);
    float*    xgr  = ws + o_xgr;
    float*    h1sp = ws + o_h1s;
    unsigned* ctr0 = (unsigned*)(ws + o_flg);
    unsigned* flagW = ctr0 + 32 * 16;
    unsigned* ctr1  = flagW + 32 * 64;

    hipMemsetAsync(ctr0, 0, (32 * 16 + 32 * 64 + 32 * 16) * sizeof(unsigned),
                   stream);

    void* args[] = {
        (void*)&x,
        (void*)&w_hh0, (void*)&w_hh1,
        (void*)&w_ih0, (void*)&b_ih0, (void*)&b_hh0,
        (void*)&w_ih1, (void*)&b_ih1, (void*)&b_hh1,
        (void*)&fc1w, (void*)&fc1b, (void*)&fc2w, (void*)&fc2b,
        (void*)&h0pl, (void*)&xgr, (void*)&h1sp, (void*)&out,
        (void*)&ctr0, (void*)&flagW, (void*)&ctr1,
    };
    hipLaunchCooperativeKernel((const void*)fused, dim3(256), dim3(512),
                               args, 0, stream);
}

// Round 11
// 722.369 us; speedup vs baseline: 3.8936x; 1.0037x over previous
//
#include <hip/hip_runtime.h>

#define NB 512
#define NT 256
#define NI 32
#define NH 128
#define NG 512
#define WIN 4            // steps per xg1 window
#define NWIN 64          // NT/WIN
#define RING 16          // xg1 ring slots (windows)
#define NWRK 192         // gemm worker blocks

#define L2E  1.4426950408889634f
#define L2E2 2.8853900817779268f

typedef __attribute__((ext_vector_type(8))) short bf16x8;
typedef __attribute__((ext_vector_type(4))) float f32x4;
typedef unsigned long long u64;

__device__ __forceinline__ unsigned short f2bf_rne(float f) {
    unsigned u = __float_as_uint(f);
    return (unsigned short)((u + 0x7FFFu + ((u >> 16) & 1u)) >> 16);
}
__device__ __forceinline__ void split2(float a, float b, unsigned& hi, unsigned& lo) {
    unsigned short ha = f2bf_rne(a), hb = f2bf_rne(b);
    float ra = a - __uint_as_float((unsigned)ha << 16);
    float rb = b - __uint_as_float((unsigned)hb << 16);
    hi = (unsigned)ha | ((unsigned)hb << 16);
    lo = (unsigned)f2bf_rne(ra) | ((unsigned)f2bf_rne(rb) << 16);
}
__device__ __forceinline__ bf16x8 u4bf(uint4 u) {
    union { uint4 u; bf16x8 v; } c; c.u = u; return c.v;
}
#define MFMA16(accv, av, bv) \
    accv = __builtin_amdgcn_mfma_f32_16x16x32_bf16(av, bv, accv, 0, 0, 0)

__device__ __forceinline__ void lds_barrier() {
    asm volatile("s_waitcnt lgkmcnt(0)\n\ts_barrier" ::: "memory");
}
__device__ __forceinline__ void vm_drain() {
    asm volatile("s_waitcnt vmcnt(0)" ::: "memory");
}
// Lazy release: only ops OLDER than the most recent 8 vmem ops must be done.
// role0 issues exactly 4 vmem ops/step (2 x-loads + 2 atomic exports), so
// this waits for stores >=2 steps old (>=3us) -> effectively free, yet
// everything covered by the lagged counter (t-4) is guaranteed visible.
__device__ __forceinline__ void vm_lazy8() {
    asm volatile("s_waitcnt vmcnt(8)" ::: "memory");
}

// AGENT-scope relaxed atomics: each access goes to the coherence point (LLC),
// cross-XCD safe with NO fences and NO L2 writebacks. (R24's attempt to
// replace these with plain sc0|sc1 16B ops FAILED correctness: the plain-op
// ack/visibility semantics are not equivalent. Atomics are the proven path.)
__device__ __forceinline__ u64 ald64(const u64* p) {
    return __hip_atomic_load(p, __ATOMIC_RELAXED, __HIP_MEMORY_SCOPE_AGENT);
}
__device__ __forceinline__ void ast64(u64* p, u64 v) {
    __hip_atomic_store(p, v, __ATOMIC_RELAXED, __HIP_MEMORY_SCOPE_AGENT);
}
__device__ __forceinline__ unsigned aldu(const unsigned* p) {
    return __hip_atomic_load(p, __ATOMIC_RELAXED, __HIP_MEMORY_SCOPE_AGENT);
}
__device__ __forceinline__ void astu(unsigned* p, unsigned v) {
    __hip_atomic_store(p, v, __ATOMIC_RELAXED, __HIP_MEMORY_SCOPE_AGENT);
}

// fused activation: inputs m_* = -(log2e-scaled preact); updates c, returns h
__device__ __forceinline__ float activ(float mi, float mf, float mg, float mo,
                                       float& c) {
    float ei = exp2f(mi), ef = exp2f(mf), eg = exp2f(mg), eo = exp2f(mo);
    float rf  = __builtin_amdgcn_rcpf(1.0f + ef);
    float rig = __builtin_amdgcn_rcpf((1.0f + ei) * (1.0f + eg));
    float cn  = c * rf + (1.0f - eg) * rig;
    c = cn;
    float ec = exp2f(cn * -L2E2);
    float rh = __builtin_amdgcn_rcpf((1.0f + eo) * (1.0f + ec));
    return (1.0f - ec) * rh;
}

// ---------------------------------------------------------------------------
// R25 = R22 (proven 725us) + worker weight-reuse.
// R22 counters: FETCH 176MB, of which ~67MB is w_ih1 HBM re-fetch — each of
// 2048 tiles re-read + re-converted all 256KB of w_ih1 (512MB L2 traffic +
// ~1us split2 VALU per tile). Worker blocks persist across ~10.7 tiles ->
// hoist the split-bf16 B-fragments into registers ONCE per block (128 VGPR;
// worker peak ~245 < 256; roles unaffected — already 1 block/CU).
// A-loads restructured per-tt chunk (32 VGPR live) to fit. All transport,
// flag protocol, and role code byte-identical to R22.
// ---------------------------------------------------------------------------
__global__ __launch_bounds__(512, 1)
void fused(const float* __restrict__ x,
           const float* __restrict__ w_hh0, const float* __restrict__ w_hh1,
           const float* __restrict__ w_ih0, const float* __restrict__ b_ih0,
           const float* __restrict__ b_hh0,
           const float* __restrict__ w_ih1, const float* __restrict__ b_ih1,
           const float* __restrict__ b_hh1,
           const float* __restrict__ fc1w, const float* __restrict__ fc1b,
           const float* __restrict__ fc2w, const float* __restrict__ fc2b,
           u64* __restrict__ h0pl,                 // [256][2][32][512] u64
           float* __restrict__ xgr,                // ring, coalesced layout
           float* __restrict__ h1s, float* __restrict__ out,
           unsigned* __restrict__ ctr0, unsigned* __restrict__ flagW,
           unsigned* __restrict__ ctr1)
{
    __shared__ __align__(16) unsigned short HA[2][16][128];   // 8 KB
    __shared__ __align__(16) unsigned short HL[2][16][128];   // 8 KB

    const int bid  = blockIdx.x;
    const int tid  = threadIdx.x;
    const int wv   = tid >> 6;
    const int lane = tid & 63;
    const int quad = lane >> 4;
    const int ml   = lane & 15;

    // =====================================================================
    if (bid >= 64) {                       // ---------------- GEMM workers
        const int wk = bid - 64;

        // ---- hoisted tile-invariant state: W_ih1 frags + scaled bias ----
        bf16x8 bh[4][4], bl[4][4];         // [nt][q], 128 VGPR
        float nbs[4], sg[4];
#pragma unroll
        for (int nt = 0; nt < 4; ++nt) {
            int n = wv * 64 + nt * 16 + ml;
            float s = ((n >> 7) == 2) ? L2E2 : L2E;
            sg[nt]  = s;
            nbs[nt] = -(b_ih1[n] + b_hh1[n]) * s;
            const float* bw = w_ih1 + (size_t)n * NH + quad * 8;
#pragma unroll
            for (int q = 0; q < 4; ++q) {
                float4 v0 = *(const float4*)(bw + q * 32);
                float4 v1 = *(const float4*)(bw + q * 32 + 4);
                uint4 H, L;
                split2(v0.x, v0.y, H.x, L.x); split2(v0.z, v0.w, H.y, L.y);
                split2(v1.x, v1.y, H.z, L.z); split2(v1.z, v1.w, H.w, L.w);
                bh[nt][q] = u4bf(H); bl[nt][q] = u4bf(L);
            }
        }

        for (int tile = wk; tile < 32 * NWIN; tile += NWRK) {
            const int w  = tile >> 5;
            const int pp = tile & 31;
            while (aldu(&ctr0[pp * 16]) < (unsigned)(4 * w + 4))
                __builtin_amdgcn_s_sleep(8);
            if (w >= RING)
                while (aldu(&ctr1[pp * 16]) < (unsigned)(w - (RING - 1)))
                    __builtin_amdgcn_s_sleep(8);
            asm volatile("" ::: "memory");

            f32x4 acc[4][4] = {};          // [tt][nt]
#pragma unroll
            for (int tt = 0; tt < 4; ++tt) {
                // A-frags for this timestep only (32 VGPR live)
                bf16x8 A[4][2];            // [q][plane]
#pragma unroll
                for (int q = 0; q < 4; ++q)
#pragma unroll
                    for (int pl = 0; pl < 2; ++pl) {
                        const u64* ap =
                            h0pl + (((size_t)(4 * w + tt) * 2 + pl) * 32 + pp) * 512
                                 + ml * 32 + q * 8 + quad * 2;
                        u64 a0 = ald64(ap), a1 = ald64(ap + 1);
                        uint4 U;
                        U.x = (unsigned)a0; U.y = (unsigned)(a0 >> 32);
                        U.z = (unsigned)a1; U.w = (unsigned)(a1 >> 32);
                        A[q][pl] = u4bf(U);
                    }
#pragma unroll
                for (int nt = 0; nt < 4; ++nt)
#pragma unroll
                    for (int q = 0; q < 4; ++q) {
                        MFMA16(acc[tt][nt], A[q][0], bh[nt][q]);
                        MFMA16(acc[tt][nt], A[q][1], bh[nt][q]);
                        MFMA16(acc[tt][nt], A[q][0], bl[nt][q]);
                    }
            }

            // ring store, coalesced layout (R21/R22-proven, ast64):
            //   addr(tt,n,m) = tt*8192 + (m>>2)*2048 + (n>>7)*512
            //                + (n&127)*4 + (m&3)
            const int slot = w & (RING - 1);
            float* cb = xgr + ((size_t)slot * 32 + pp) * WIN * 8192;
#pragma unroll
            for (int nt = 0; nt < 4; ++nt) {
                int n = wv * 64 + nt * 16 + ml;
                int aoff = quad * 2048 + (n >> 7) * 512 + (n & 127) * 4;
#pragma unroll
                for (int tt = 0; tt < 4; ++tt) {
                    float* cp = cb + (size_t)tt * 8192 + aoff;
                    float v0 = fmaf(acc[tt][nt][0], -sg[nt], nbs[nt]);
                    float v1 = fmaf(acc[tt][nt][1], -sg[nt], nbs[nt]);
                    float v2 = fmaf(acc[tt][nt][2], -sg[nt], nbs[nt]);
                    float v3 = fmaf(acc[tt][nt][3], -sg[nt], nbs[nt]);
                    ast64((u64*)cp,
                          (u64)__float_as_uint(v0) |
                          ((u64)__float_as_uint(v1) << 32));
                    ast64((u64*)(cp + 2),
                          (u64)__float_as_uint(v2) |
                          ((u64)__float_as_uint(v3) << 32));
                }
            }
            vm_drain();
            __syncthreads();
            if (tid == 0) astu(&flagW[pp * 64 + w], 1u);
        }
        return;
    }

    // =====================================================================
    // recurrence roles
    const int role = bid >> 5;
    const int p    = bid & 31;
    const int j    = 16 * wv + ml;
    const float* wsrc = role ? w_hh1 : w_hh0;

    bf16x8 wh[4][4], wl[4][4];
#pragma unroll
    for (int t = 0; t < 4; ++t) {
        const float sc = (t == 2) ? L2E2 : L2E;
#pragma unroll
        for (int q = 0; q < 4; ++q) {
            int n = (t * 8 + wv) * 16 + ml;
            const float* s = wsrc + (size_t)n * NH + q * 32 + quad * 8;
            float4 v0 = *(const float4*)s;
            float4 v1 = *(const float4*)(s + 4);
            uint4 H, L;
            split2(v0.x * sc, v0.y * sc, H.x, L.x); split2(v0.z * sc, v0.w * sc, H.y, L.y);
            split2(v1.x * sc, v1.y * sc, H.z, L.z); split2(v1.z * sc, v1.w * sc, H.w, L.w);
            wh[t][q] = u4bf(H);
            wl[t][q] = u4bf(L);
        }
    }

    int ro[4];
#pragma unroll
    for (int q = 0; q < 4; ++q)
        ro[q] = ((ml * 256 + q * 64 + quad * 16) ^ ((ml & 7) << 4));
    int wo[4];
#pragma unroll
    for (int r = 0; r < 4; ++r) {
        int m = quad * 4 + r;
        wo[r] = ((m * 256 + j * 2) ^ ((m & 7) << 4));
    }

    float cr[4] = {};
#pragma unroll
    for (int r = 0; r < 4; ++r) {
        *(unsigned short*)((char*)&HA[0][0][0] + wo[r]) = 0;
        *(unsigned short*)((char*)&HL[0][0][0] + wo[r]) = 0;
    }
    __syncthreads();

    if (role == 0) {
        // ================= role0: layer0, fused x-GEMM, h0 export ========
        bf16x8 wi_h[4], wi_l[4];
        float nb[4];
#pragma unroll
        for (int t = 0; t < 4; ++t) {
            const float sc = (t == 2) ? L2E2 : L2E;
            int n = (t * 8 + wv) * 16 + ml;
            const float* s = w_ih0 + (size_t)n * NI + quad * 8;
            float4 v0 = *(const float4*)s;
            float4 v1 = *(const float4*)(s + 4);
            uint4 H, L;
            split2(v0.x * sc, v0.y * sc, H.x, L.x); split2(v0.z * sc, v0.w * sc, H.y, L.y);
            split2(v1.x * sc, v1.y * sc, H.z, L.z); split2(v1.z * sc, v1.w * sc, H.w, L.w);
            wi_h[t] = u4bf(H);
            wi_l[t] = u4bf(L);
            int nn = t * 128 + j;
            nb[t] = -(b_ih0[nn] + b_hh0[nn]) * sc;
        }

        const int erow = tid >> 5;
        const int eoff = erow * 256 + (((tid & 31) * 8) ^ ((erow & 7) << 4));

        const float* xrow = x + (size_t)(p * 16 + ml) * NT * NI + quad * 8;
        auto xload = [&](float4& a, float4& b, int T) __attribute__((always_inline)) {
            const float* sp = xrow + (size_t)T * NI;
            a = *(const float4*)sp;
            b = *(const float4*)(sp + 4);
        };

        auto exp0 = [&](int T, int BUF) __attribute__((always_inline)) {
            // export h_{T-1} (resident in HA/HL[BUF]) -> linear [m][j] planes
            u64 vh = *(const u64*)((const char*)&HA[BUF][0][0] + eoff);
            u64 vl = *(const u64*)((const char*)&HL[BUF][0][0] + eoff);
            ast64(h0pl + (((size_t)(T - 1) * 2 + 0) * 32 + p) * 512 + tid, vh);
            ast64(h0pl + (((size_t)(T - 1) * 2 + 1) * 32 + p) * 512 + tid, vl);
        };

        auto step0 = [&](int TL, int BUF, float4 x0, float4 x1)
            __attribute__((always_inline)) {
            const char* hb = (const char*)&HA[BUF][0][0];
            const char* lb = (const char*)&HL[BUF][0][0];
            char* hbn = (char*)&HA[BUF ^ 1][0][0];
            char* lbn = (char*)&HL[BUF ^ 1][0][0];
            uint4 XH, XL;
            split2(x0.x, x0.y, XH.x, XL.x); split2(x0.z, x0.w, XH.y, XL.y);
            split2(x1.x, x1.y, XH.z, XL.z); split2(x1.z, x1.w, XH.w, XL.w);
            bf16x8 xh = u4bf(XH), xl = u4bf(XL);
            f32x4 P[4] = {}, Q[4] = {};
#pragma unroll
            for (int t = 0; t < 4; ++t) {
                MFMA16(P[t], xh, wi_h[t]);
                MFMA16(Q[t], xl, wi_h[t]);
                MFMA16(Q[t], xh, wi_l[t]);
            }
#pragma unroll
            for (int q = 0; q < 4; ++q) {
                bf16x8 ah = *(const bf16x8*)(hb + ro[q]);
                bf16x8 al = *(const bf16x8*)(lb + ro[q]);
#pragma unroll
                for (int t = 0; t < 4; ++t) {
                    MFMA16(P[t], ah, wh[t][q]);
                    MFMA16(Q[t], al, wh[t][q]);
                    if (q & 1) { MFMA16(P[t], ah, wl[t][q]); }
                    else       { MFMA16(Q[t], ah, wl[t][q]); }
                }
            }
#pragma unroll
            for (int r = 0; r < 4; ++r) {
                float mi = nb[0] - P[0][r] - Q[0][r];
                float mf = nb[1] - P[1][r] - Q[1][r];
                float mg = nb[2] - P[2][r] - Q[2][r];
                float mo = nb[3] - P[3][r] - Q[3][r];
                float hn = activ(mi, mf, mg, mo, cr[r]);
                unsigned short hi = f2bf_rne(hn);
                float res = hn - __uint_as_float((unsigned)hi << 16);
                unsigned short lo = f2bf_rne(res);
                *(unsigned short*)(hbn + wo[r]) = hi;
                *(unsigned short*)(lbn + wo[r]) = lo;
            }
        };

        float4 xa0, xa1, xb0, xb1;
        xload(xa0, xa1, 0);
        for (int t = 0; t < 256; t += 2) {
            if (t > 0) {
                exp0(t, 0);
                if ((t & 3) == 0) {
                    vm_lazy8();            // waits only for ops >=2 steps old
                    __syncthreads();
                    if (tid == 0 && t >= 8)
                        astu(&ctr0[p * 16], (unsigned)(t - 4));  // lagged publish
                }
            }
            xload(xb0, xb1, t + 1);
            step0(t, 0, xa0, xa1);
            lds_barrier();
            exp0(t + 1, 1);
            xload(xa0, xa1, t + 2 > 255 ? 255 : t + 2);
            step0(t + 1, 1, xb0, xb1);
            lds_barrier();
        }
        exp0(256, 0);                      // h_255
        vm_drain();
        __syncthreads();
        if (tid == 0) astu(&ctr0[p * 16], 256u);
        return;
    }

    // ================= role1: layer1 recurrence + fc head ================
    {
        // coalesced ring read: value(n = tg*128+j, m = quad*4+r) at
        //   tt*8192 + quad*2048 + tg*512 + j*4 + r
        auto pxg = [&](float (&d)[4][4], int u) __attribute__((always_inline)) {
            int uc = u < 255 ? u : 255;
            int slot = (uc >> 2) & (RING - 1);
            int tt   = uc & 3;
            const float* b = xgr + (((size_t)slot * 32 + p) * WIN + tt) * 8192
                                 + quad * 2048 + j * 4;
#pragma unroll
            for (int tg = 0; tg < 4; ++tg) {
                u64 a0 = ald64((const u64*)(b + tg * 512));
                u64 a1 = ald64((const u64*)(b + tg * 512 + 2));
                d[tg][0] = __uint_as_float((unsigned)a0);
                d[tg][1] = __uint_as_float((unsigned)(a0 >> 32));
                d[tg][2] = __uint_as_float((unsigned)a1);
                d[tg][3] = __uint_as_float((unsigned)(a1 >> 32));
            }
        };

        auto step1 = [&](int TL, int BUF, const float (&xgv)[4][4])
            __attribute__((always_inline)) {
            const char* hb = (const char*)&HA[BUF][0][0];
            const char* lb = (const char*)&HL[BUF][0][0];
            char* hbn = (char*)&HA[BUF ^ 1][0][0];
            char* lbn = (char*)&HL[BUF ^ 1][0][0];
            f32x4 P[4] = {}, Q[4] = {};
#pragma unroll
            for (int q = 0; q < 4; ++q) {
                bf16x8 ah = *(const bf16x8*)(hb + ro[q]);
                bf16x8 al = *(const bf16x8*)(lb + ro[q]);
#pragma unroll
                for (int t = 0; t < 4; ++t) {
                    MFMA16(P[t], ah, wh[t][q]);
                    MFMA16(Q[t], al, wh[t][q]);
                    if (q & 1) { MFMA16(P[t], ah, wl[t][q]); }
                    else       { MFMA16(Q[t], ah, wl[t][q]); }
                }
            }
#pragma unroll
            for (int r = 0; r < 4; ++r) {
                float mi = xgv[0][r] - P[0][r] - Q[0][r];
                float mf = xgv[1][r] - P[1][r] - Q[1][r];
                float mg = xgv[2][r] - P[2][r] - Q[2][r];
                float mo = xgv[3][r] - P[3][r] - Q[3][r];
                float hn = activ(mi, mf, mg, mo, cr[r]);
                unsigned short hi = f2bf_rne(hn);
                float res = hn - __uint_as_float((unsigned)hi << 16);
                unsigned short lo = f2bf_rne(res);
                *(unsigned short*)(hbn + wo[r]) = hi;
                *(unsigned short*)(lbn + wo[r]) = lo;
                if (TL == 255)
                    h1s[(size_t)(p * 16 + quad * 4 + r) * NH + j] = hn;
            }
        };

        auto waitflag = [&](int wn) __attribute__((always_inline)) {
            if (tid == 0) {
                while (aldu(&flagW[p * 64 + wn]) == 0)
                    __builtin_amdgcn_s_sleep(1);
            }
            __syncthreads();
            asm volatile("" ::: "memory");
        };

        // prologue: window 0 ready, load steps 0 and 1 (distance-2 pipeline)
        waitflag(0);
        float xa[4][4], xb[4][4], xc[4][4], xd[4][4];
        pxg(xa, 0);
        pxg(xb, 1);

        for (int u = 0; u < 256; u += 4) {
            if (u > 0 && tid == 0) astu(&ctr1[p * 16], (unsigned)(u >> 2));
            pxg(xc, u + 2);                  // same window as u (u%4==0)
            step1(u, 0, xa);
            lds_barrier();
            pxg(xd, u + 3);
            step1(u + 1, 1, xb);
            lds_barrier();
            if (u + 4 < 256) waitflag((u + 4) >> 2);
            pxg(xa, u + 4);                  // next window (clamped at end)
            step1(u + 2, 0, xc);
            lds_barrier();
            pxg(xb, u + 5);
            step1(u + 3, 1, xd);
            lds_barrier();
        }

        // fc head: out[b] = fc2 . relu(fc1 @ h1_last + b1) + b2
        vm_drain();
        __syncthreads();
        const int g = tid >> 5;
        const int l = tid & 31;
        const float4* h4 = (const float4*)(h1s + (size_t)(p * 16 + g) * NH);
        const float4* w0 = (const float4*)(fc1w + (size_t)l * NH);
        const float4* w1 = (const float4*)(fc1w + (size_t)(l + 32) * NH);
        float a0 = fc1b[l], a1 = fc1b[l + 32];
#pragma unroll
        for (int q = 0; q < 32; ++q) {
            float4 h = h4[q], u = w0[q], v = w1[q];
            a0 += u.x * h.x + u.y * h.y + u.z * h.z + u.w * h.w;
            a1 += v.x * h.x + v.y * h.y + v.z * h.z + v.w * h.w;
        }
        float pv = fc2w[l] * fmaxf(a0, 0.f) + fc2w[l + 32] * fmaxf(a1, 0.f);
#pragma unroll
        for (int off = 16; off > 0; off >>= 1) pv += __shfl_down(pv, off, 32);
        if (l == 0) out[p * 16 + g] = pv + fc2b[0];
    }
}

extern "C" void kernel_launch(void* const* d_in, const int* in_sizes, int n_in,
                              void* d_out, int out_size, void* d_ws, size_t ws_size,
                              hipStream_t stream)
{
    const float* x     = (const float*)d_in[0];
    const float* w_ih0 = (const float*)d_in[1];
    const float* w_hh0 = (const float*)d_in[2];
    const float* b_ih0 = (const float*)d_in[3];
    const float* b_hh0 = (const float*)d_in[4];
    const float* w_ih1 = (const float*)d_in[5];
    const float* w_hh1 = (const float*)d_in[6];
    const float* b_ih1 = (const float*)d_in[7];
    const float* b_hh1 = (const float*)d_in[8];
    const float* fc1w  = (const float*)d_in[9];
    const float* fc1b  = (const float*)d_in[10];
    const float* fc2w  = (const float*)d_in[11];
    const float* fc2b  = (const float*)d_in[12];
    float* out = (float*)d_out;
    float* ws  = (float*)d_ws;

    // ws layout (floats):
    //  h0 planes: 256 t x 2 pl x 32 p x 4KB  = 16.78M floats (64 MB)
    //  xg ring  : RING x 32 p x WIN x 8192   = 16.78M floats (64 MB)
    //  h1s 64K | flags 3072 u32  -> total ~134.5 MB (<= proven 152 MB ws)
    size_t o_h0  = 0;
    size_t o_xgr = o_h0 + (size_t)256 * 2 * 32 * 1024;   // u64 count*2 floats
    size_t o_h1s = o_xgr + (size_t)RING * 32 * WIN * 8192;
    size_t o_flg = o_h1s + (size_t)NB * NH;

    u64*      h0pl = (u64*)(ws + o_h0);
    float*    xgr  = ws + o_xgr;
    float*    h1sp = ws + o_h1s;
    unsigned* ctr0 = (unsigned*)(ws + o_flg);
    unsigned* flagW = ctr0 + 32 * 16;
    unsigned* ctr1  = flagW + 32 * 64;

    hipMemsetAsync(ctr0, 0, (32 * 16 + 32 * 64 + 32 * 16) * sizeof(unsigned),
                   stream);

    void* args[] = {
        (void*)&x,
        (void*)&w_hh0, (void*)&w_hh1,
        (void*)&w_ih0, (void*)&b_ih0, (void*)&b_hh0,
        (void*)&w_ih1, (void*)&b_ih1, (void*)&b_hh1,
        (void*)&fc1w, (void*)&fc1b, (void*)&fc2w, (void*)&fc2b,
        (void*)&h0pl, (void*)&xgr, (void*)&h1sp, (void*)&out,
        (void*)&ctr0, (void*)&flagW, (void*)&ctr1,
    };
    hipLaunchCooperativeKernel((const void*)fused, dim3(256), dim3(512),
                               args, 0, stream);
}

// Round 12
// 715.346 us; speedup vs baseline: 3.9318x; 1.0098x over previous
//
#include <hip/hip_runtime.h>

#define NB 512
#define NT 256
#define NI 32
#define NH 128
#define NG 512
#define WIN 4            // steps per xg1 window
#define NWIN 64          // NT/WIN
#define RING 16          // xg1 ring slots (windows)
#define NWRK 192         // gemm worker blocks

#define L2E  1.4426950408889634f
#define L2E2 2.8853900817779268f

typedef __attribute__((ext_vector_type(8))) short bf16x8;
typedef __attribute__((ext_vector_type(4))) float f32x4;
typedef unsigned long long u64;

__device__ __forceinline__ unsigned short f2bf_rne(float f) {
    unsigned u = __float_as_uint(f);
    return (unsigned short)((u + 0x7FFFu + ((u >> 16) & 1u)) >> 16);
}
__device__ __forceinline__ void split2(float a, float b, unsigned& hi, unsigned& lo) {
    unsigned short ha = f2bf_rne(a), hb = f2bf_rne(b);
    float ra = a - __uint_as_float((unsigned)ha << 16);
    float rb = b - __uint_as_float((unsigned)hb << 16);
    hi = (unsigned)ha | ((unsigned)hb << 16);
    lo = (unsigned)f2bf_rne(ra) | ((unsigned)f2bf_rne(rb) << 16);
}
__device__ __forceinline__ bf16x8 u4bf(uint4 u) {
    union { uint4 u; bf16x8 v; } c; c.u = u; return c.v;
}
#define MFMA16(accv, av, bv) \
    accv = __builtin_amdgcn_mfma_f32_16x16x32_bf16(av, bv, accv, 0, 0, 0)

__device__ __forceinline__ void lds_barrier() {
    asm volatile("s_waitcnt lgkmcnt(0)\n\ts_barrier" ::: "memory");
}
__device__ __forceinline__ void vm_drain() {
    asm volatile("s_waitcnt vmcnt(0)" ::: "memory");
}
// Lazy release: waits only for ops older than the newest 6 vmem ops.
// role0 issues 4 vmem ops/step; at the publish point the newest 6 are the
// current exp0 (2) + previous step (4) -> everything through step t-2 is
// retired, so publishing ctr0 = t-2 (planes <= t-3 visible) is safe AND the
// wait targets ~2-step-old (>=5us) stores -> effectively free.
__device__ __forceinline__ void vm_lazy6() {
    asm volatile("s_waitcnt vmcnt(6)" ::: "memory");
}

// AGENT-scope relaxed atomics: each access goes to the coherence point (LLC),
// cross-XCD safe with NO fences and NO L2 writebacks. (R24 showed plain
// sc0|sc1 ops are NOT semantically equivalent: atomics are the proven path.)
__device__ __forceinline__ u64 ald64(const u64* p) {
    return __hip_atomic_load(p, __ATOMIC_RELAXED, __HIP_MEMORY_SCOPE_AGENT);
}
__device__ __forceinline__ void ast64(u64* p, u64 v) {
    __hip_atomic_store(p, v, __ATOMIC_RELAXED, __HIP_MEMORY_SCOPE_AGENT);
}
__device__ __forceinline__ unsigned aldu(const unsigned* p) {
    return __hip_atomic_load(p, __ATOMIC_RELAXED, __HIP_MEMORY_SCOPE_AGENT);
}
__device__ __forceinline__ void astu(unsigned* p, unsigned v) {
    __hip_atomic_store(p, v, __ATOMIC_RELAXED, __HIP_MEMORY_SCOPE_AGENT);
}

// fused activation: inputs m_* = -(log2e-scaled preact); updates c, returns h
__device__ __forceinline__ float activ(float mi, float mf, float mg, float mo,
                                       float& c) {
    float ei = exp2f(mi), ef = exp2f(mf), eg = exp2f(mg), eo = exp2f(mo);
    float rf  = __builtin_amdgcn_rcpf(1.0f + ef);
    float rig = __builtin_amdgcn_rcpf((1.0f + ei) * (1.0f + eg));
    float cn  = c * rf + (1.0f - eg) * rig;
    c = cn;
    float ec = exp2f(cn * -L2E2);
    float rh = __builtin_amdgcn_rcpf((1.0f + eo) * (1.0f + ec));
    return (1.0f - ec) * rh;
}

// ---------------------------------------------------------------------------
// R26 = R25 (proven 722us) + gated worker polling (congestion discriminator).
// Null ledger: role1 prefetch depth (R21), ring coalescing (R21), role0
// publish drain (R22), worker weights (R25) -> role0 free-runs at ~2.45us/step
// in the persistent kernel vs ~1.6 in chunked dispatches. Last cheap suspect:
// ALL 512 threads of 192 worker blocks spin on 32 hot LLC flag lines
// (~5G agent-scope reads/s) sharing fabric ports + LLC slices with the roles'
// exports and ring reads. Fix: tid0-only poll + syncthreads + s_sleep(16).
// Also: publish lag tightened t-4 -> t-2 via vmcnt(6) (tail -5us, free).
// Everything else byte-identical to R25.
// ---------------------------------------------------------------------------
__global__ __launch_bounds__(512, 1)
void fused(const float* __restrict__ x,
           const float* __restrict__ w_hh0, const float* __restrict__ w_hh1,
           const float* __restrict__ w_ih0, const float* __restrict__ b_ih0,
           const float* __restrict__ b_hh0,
           const float* __restrict__ w_ih1, const float* __restrict__ b_ih1,
           const float* __restrict__ b_hh1,
           const float* __restrict__ fc1w, const float* __restrict__ fc1b,
           const float* __restrict__ fc2w, const float* __restrict__ fc2b,
           u64* __restrict__ h0pl,                 // [256][2][32][512] u64
           float* __restrict__ xgr,                // ring, coalesced layout
           float* __restrict__ h1s, float* __restrict__ out,
           unsigned* __restrict__ ctr0, unsigned* __restrict__ flagW,
           unsigned* __restrict__ ctr1)
{
    __shared__ __align__(16) unsigned short HA[2][16][128];   // 8 KB
    __shared__ __align__(16) unsigned short HL[2][16][128];   // 8 KB

    const int bid  = blockIdx.x;
    const int tid  = threadIdx.x;
    const int wv   = tid >> 6;
    const int lane = tid & 63;
    const int quad = lane >> 4;
    const int ml   = lane & 15;

    // =====================================================================
    if (bid >= 64) {                       // ---------------- GEMM workers
        const int wk = bid - 64;

        // ---- hoisted tile-invariant state: W_ih1 frags + scaled bias ----
        bf16x8 bh[4][4], bl[4][4];         // [nt][q], 128 VGPR
        float nbs[4], sg[4];
#pragma unroll
        for (int nt = 0; nt < 4; ++nt) {
            int n = wv * 64 + nt * 16 + ml;
            float s = ((n >> 7) == 2) ? L2E2 : L2E;
            sg[nt]  = s;
            nbs[nt] = -(b_ih1[n] + b_hh1[n]) * s;
            const float* bw = w_ih1 + (size_t)n * NH + quad * 8;
#pragma unroll
            for (int q = 0; q < 4; ++q) {
                float4 v0 = *(const float4*)(bw + q * 32);
                float4 v1 = *(const float4*)(bw + q * 32 + 4);
                uint4 H, L;
                split2(v0.x, v0.y, H.x, L.x); split2(v0.z, v0.w, H.y, L.y);
                split2(v1.x, v1.y, H.z, L.z); split2(v1.z, v1.w, H.w, L.w);
                bh[nt][q] = u4bf(H); bl[nt][q] = u4bf(L);
            }
        }

        for (int tile = wk; tile < 32 * NWIN; tile += NWRK) {
            const int w  = tile >> 5;
            const int pp = tile & 31;
            // gated poll: ONE thread watches the LLC flag lines (was 512)
            if (tid == 0) {
                while (aldu(&ctr0[pp * 16]) < (unsigned)(4 * w + 4))
                    __builtin_amdgcn_s_sleep(16);
                if (w >= RING)
                    while (aldu(&ctr1[pp * 16]) < (unsigned)(w - (RING - 1)))
                        __builtin_amdgcn_s_sleep(16);
            }
            __syncthreads();
            asm volatile("" ::: "memory");

            f32x4 acc[4][4] = {};          // [tt][nt]
#pragma unroll
            for (int tt = 0; tt < 4; ++tt) {
                // A-frags for this timestep only (32 VGPR live)
                bf16x8 A[4][2];            // [q][plane]
#pragma unroll
                for (int q = 0; q < 4; ++q)
#pragma unroll
                    for (int pl = 0; pl < 2; ++pl) {
                        const u64* ap =
                            h0pl + (((size_t)(4 * w + tt) * 2 + pl) * 32 + pp) * 512
                                 + ml * 32 + q * 8 + quad * 2;
                        u64 a0 = ald64(ap), a1 = ald64(ap + 1);
                        uint4 U;
                        U.x = (unsigned)a0; U.y = (unsigned)(a0 >> 32);
                        U.z = (unsigned)a1; U.w = (unsigned)(a1 >> 32);
                        A[q][pl] = u4bf(U);
                    }
#pragma unroll
                for (int nt = 0; nt < 4; ++nt)
#pragma unroll
                    for (int q = 0; q < 4; ++q) {
                        MFMA16(acc[tt][nt], A[q][0], bh[nt][q]);
                        MFMA16(acc[tt][nt], A[q][1], bh[nt][q]);
                        MFMA16(acc[tt][nt], A[q][0], bl[nt][q]);
                    }
            }

            // ring store, coalesced layout (R21/R22-proven, ast64):
            //   addr(tt,n,m) = tt*8192 + (m>>2)*2048 + (n>>7)*512
            //                + (n&127)*4 + (m&3)
            const int slot = w & (RING - 1);
            float* cb = xgr + ((size_t)slot * 32 + pp) * WIN * 8192;
#pragma unroll
            for (int nt = 0; nt < 4; ++nt) {
                int n = wv * 64 + nt * 16 + ml;
                int aoff = quad * 2048 + (n >> 7) * 512 + (n & 127) * 4;
#pragma unroll
                for (int tt = 0; tt < 4; ++tt) {
                    float* cp = cb + (size_t)tt * 8192 + aoff;
                    float v0 = fmaf(acc[tt][nt][0], -sg[nt], nbs[nt]);
                    float v1 = fmaf(acc[tt][nt][1], -sg[nt], nbs[nt]);
                    float v2 = fmaf(acc[tt][nt][2], -sg[nt], nbs[nt]);
                    float v3 = fmaf(acc[tt][nt][3], -sg[nt], nbs[nt]);
                    ast64((u64*)cp,
                          (u64)__float_as_uint(v0) |
                          ((u64)__float_as_uint(v1) << 32));
                    ast64((u64*)(cp + 2),
                          (u64)__float_as_uint(v2) |
                          ((u64)__float_as_uint(v3) << 32));
                }
            }
            vm_drain();
            __syncthreads();
            if (tid == 0) astu(&flagW[pp * 64 + w], 1u);
        }
        return;
    }

    // =====================================================================
    // recurrence roles
    const int role = bid >> 5;
    const int p    = bid & 31;
    const int j    = 16 * wv + ml;
    const float* wsrc = role ? w_hh1 : w_hh0;

    bf16x8 wh[4][4], wl[4][4];
#pragma unroll
    for (int t = 0; t < 4; ++t) {
        const float sc = (t == 2) ? L2E2 : L2E;
#pragma unroll
        for (int q = 0; q < 4; ++q) {
            int n = (t * 8 + wv) * 16 + ml;
            const float* s = wsrc + (size_t)n * NH + q * 32 + quad * 8;
            float4 v0 = *(const float4*)s;
            float4 v1 = *(const float4*)(s + 4);
            uint4 H, L;
            split2(v0.x * sc, v0.y * sc, H.x, L.x); split2(v0.z * sc, v0.w * sc, H.y, L.y);
            split2(v1.x * sc, v1.y * sc, H.z, L.z); split2(v1.z * sc, v1.w * sc, H.w, L.w);
            wh[t][q] = u4bf(H);
            wl[t][q] = u4bf(L);
        }
    }

    int ro[4];
#pragma unroll
    for (int q = 0; q < 4; ++q)
        ro[q] = ((ml * 256 + q * 64 + quad * 16) ^ ((ml & 7) << 4));
    int wo[4];
#pragma unroll
    for (int r = 0; r < 4; ++r) {
        int m = quad * 4 + r;
        wo[r] = ((m * 256 + j * 2) ^ ((m & 7) << 4));
    }

    float cr[4] = {};
#pragma unroll
    for (int r = 0; r < 4; ++r) {
        *(unsigned short*)((char*)&HA[0][0][0] + wo[r]) = 0;
        *(unsigned short*)((char*)&HL[0][0][0] + wo[r]) = 0;
    }
    __syncthreads();

    if (role == 0) {
        // ================= role0: layer0, fused x-GEMM, h0 export ========
        bf16x8 wi_h[4], wi_l[4];
        float nb[4];
#pragma unroll
        for (int t = 0; t < 4; ++t) {
            const float sc = (t == 2) ? L2E2 : L2E;
            int n = (t * 8 + wv) * 16 + ml;
            const float* s = w_ih0 + (size_t)n * NI + quad * 8;
            float4 v0 = *(const float4*)s;
            float4 v1 = *(const float4*)(s + 4);
            uint4 H, L;
            split2(v0.x * sc, v0.y * sc, H.x, L.x); split2(v0.z * sc, v0.w * sc, H.y, L.y);
            split2(v1.x * sc, v1.y * sc, H.z, L.z); split2(v1.z * sc, v1.w * sc, H.w, L.w);
            wi_h[t] = u4bf(H);
            wi_l[t] = u4bf(L);
            int nn = t * 128 + j;
            nb[t] = -(b_ih0[nn] + b_hh0[nn]) * sc;
        }

        const int erow = tid >> 5;
        const int eoff = erow * 256 + (((tid & 31) * 8) ^ ((erow & 7) << 4));

        const float* xrow = x + (size_t)(p * 16 + ml) * NT * NI + quad * 8;
        auto xload = [&](float4& a, float4& b, int T) __attribute__((always_inline)) {
            const float* sp = xrow + (size_t)T * NI;
            a = *(const float4*)sp;
            b = *(const float4*)(sp + 4);
        };

        auto exp0 = [&](int T, int BUF) __attribute__((always_inline)) {
            // export h_{T-1} (resident in HA/HL[BUF]) -> linear [m][j] planes
            u64 vh = *(const u64*)((const char*)&HA[BUF][0][0] + eoff);
            u64 vl = *(const u64*)((const char*)&HL[BUF][0][0] + eoff);
            ast64(h0pl + (((size_t)(T - 1) * 2 + 0) * 32 + p) * 512 + tid, vh);
            ast64(h0pl + (((size_t)(T - 1) * 2 + 1) * 32 + p) * 512 + tid, vl);
        };

        auto step0 = [&](int TL, int BUF, float4 x0, float4 x1)
            __attribute__((always_inline)) {
            const char* hb = (const char*)&HA[BUF][0][0];
            const char* lb = (const char*)&HL[BUF][0][0];
            char* hbn = (char*)&HA[BUF ^ 1][0][0];
            char* lbn = (char*)&HL[BUF ^ 1][0][0];
            uint4 XH, XL;
            split2(x0.x, x0.y, XH.x, XL.x); split2(x0.z, x0.w, XH.y, XL.y);
            split2(x1.x, x1.y, XH.z, XL.z); split2(x1.z, x1.w, XH.w, XL.w);
            bf16x8 xh = u4bf(XH), xl = u4bf(XL);
            f32x4 P[4] = {}, Q[4] = {};
#pragma unroll
            for (int t = 0; t < 4; ++t) {
                MFMA16(P[t], xh, wi_h[t]);
                MFMA16(Q[t], xl, wi_h[t]);
                MFMA16(Q[t], xh, wi_l[t]);
            }
#pragma unroll
            for (int q = 0; q < 4; ++q) {
                bf16x8 ah = *(const bf16x8*)(hb + ro[q]);
                bf16x8 al = *(const bf16x8*)(lb + ro[q]);
#pragma unroll
                for (int t = 0; t < 4; ++t) {
                    MFMA16(P[t], ah, wh[t][q]);
                    MFMA16(Q[t], al, wh[t][q]);
                    if (q & 1) { MFMA16(P[t], ah, wl[t][q]); }
                    else       { MFMA16(Q[t], ah, wl[t][q]); }
                }
            }
#pragma unroll
            for (int r = 0; r < 4; ++r) {
                float mi = nb[0] - P[0][r] - Q[0][r];
                float mf = nb[1] - P[1][r] - Q[1][r];
                float mg = nb[2] - P[2][r] - Q[2][r];
                float mo = nb[3] - P[3][r] - Q[3][r];
                float hn = activ(mi, mf, mg, mo, cr[r]);
                unsigned short hi = f2bf_rne(hn);
                float res = hn - __uint_as_float((unsigned)hi << 16);
                unsigned short lo = f2bf_rne(res);
                *(unsigned short*)(hbn + wo[r]) = hi;
                *(unsigned short*)(lbn + wo[r]) = lo;
            }
        };

        float4 xa0, xa1, xb0, xb1;
        xload(xa0, xa1, 0);
        for (int t = 0; t < 256; t += 2) {
            if (t > 0) {
                exp0(t, 0);
                if ((t & 3) == 0) {
                    vm_lazy6();            // ops >=2 steps old: free wait
                    __syncthreads();
                    if (tid == 0 && t >= 6)
                        astu(&ctr0[p * 16], (unsigned)(t - 2));  // lagged publish
                }
            }
            xload(xb0, xb1, t + 1);
            step0(t, 0, xa0, xa1);
            lds_barrier();
            exp0(t + 1, 1);
            xload(xa0, xa1, t + 2 > 255 ? 255 : t + 2);
            step0(t + 1, 1, xb0, xb1);
            lds_barrier();
        }
        exp0(256, 0);                      // h_255
        vm_drain();
        __syncthreads();
        if (tid == 0) astu(&ctr0[p * 16], 256u);
        return;
    }

    // ================= role1: layer1 recurrence + fc head ================
    {
        // coalesced ring read: value(n = tg*128+j, m = quad*4+r) at
        //   tt*8192 + quad*2048 + tg*512 + j*4 + r
        auto pxg = [&](float (&d)[4][4], int u) __attribute__((always_inline)) {
            int uc = u < 255 ? u : 255;
            int slot = (uc >> 2) & (RING - 1);
            int tt   = uc & 3;
            const float* b = xgr + (((size_t)slot * 32 + p) * WIN + tt) * 8192
                                 + quad * 2048 + j * 4;
#pragma unroll
            for (int tg = 0; tg < 4; ++tg) {
                u64 a0 = ald64((const u64*)(b + tg * 512));
                u64 a1 = ald64((const u64*)(b + tg * 512 + 2));
                d[tg][0] = __uint_as_float((unsigned)a0);
                d[tg][1] = __uint_as_float((unsigned)(a0 >> 32));
                d[tg][2] = __uint_as_float((unsigned)a1);
                d[tg][3] = __uint_as_float((unsigned)(a1 >> 32));
            }
        };

        auto step1 = [&](int TL, int BUF, const float (&xgv)[4][4])
            __attribute__((always_inline)) {
            const char* hb = (const char*)&HA[BUF][0][0];
            const char* lb = (const char*)&HL[BUF][0][0];
            char* hbn = (char*)&HA[BUF ^ 1][0][0];
            char* lbn = (char*)&HL[BUF ^ 1][0][0];
            f32x4 P[4] = {}, Q[4] = {};
#pragma unroll
            for (int q = 0; q < 4; ++q) {
                bf16x8 ah = *(const bf16x8*)(hb + ro[q]);
                bf16x8 al = *(const bf16x8*)(lb + ro[q]);
#pragma unroll
                for (int t = 0; t < 4; ++t) {
                    MFMA16(P[t], ah, wh[t][q]);
                    MFMA16(Q[t], al, wh[t][q]);
                    if (q & 1) { MFMA16(P[t], ah, wl[t][q]); }
                    else       { MFMA16(Q[t], ah, wl[t][q]); }
                }
            }
#pragma unroll
            for (int r = 0; r < 4; ++r) {
                float mi = xgv[0][r] - P[0][r] - Q[0][r];
                float mf = xgv[1][r] - P[1][r] - Q[1][r];
                float mg = xgv[2][r] - P[2][r] - Q[2][r];
                float mo = xgv[3][r] - P[3][r] - Q[3][r];
                float hn = activ(mi, mf, mg, mo, cr[r]);
                unsigned short hi = f2bf_rne(hn);
                float res = hn - __uint_as_float((unsigned)hi << 16);
                unsigned short lo = f2bf_rne(res);
                *(unsigned short*)(hbn + wo[r]) = hi;
                *(unsigned short*)(lbn + wo[r]) = lo;
                if (TL == 255)
                    h1s[(size_t)(p * 16 + quad * 4 + r) * NH + j] = hn;
            }
        };

        auto waitflag = [&](int wn) __attribute__((always_inline)) {
            if (tid == 0) {
                while (aldu(&flagW[p * 64 + wn]) == 0)
                    __builtin_amdgcn_s_sleep(1);
            }
            __syncthreads();
            asm volatile("" ::: "memory");
        };

        // prologue: window 0 ready, load steps 0 and 1 (distance-2 pipeline)
        waitflag(0);
        float xa[4][4], xb[4][4], xc[4][4], xd[4][4];
        pxg(xa, 0);
        pxg(xb, 1);

        for (int u = 0; u < 256; u += 4) {
            if (u > 0 && tid == 0) astu(&ctr1[p * 16], (unsigned)(u >> 2));
            pxg(xc, u + 2);                  // same window as u (u%4==0)
            step1(u, 0, xa);
            lds_barrier();
            pxg(xd, u + 3);
            step1(u + 1, 1, xb);
            lds_barrier();
            if (u + 4 < 256) waitflag((u + 4) >> 2);
            pxg(xa, u + 4);                  // next window (clamped at end)
            step1(u + 2, 0, xc);
            lds_barrier();
            pxg(xb, u + 5);
            step1(u + 3, 1, xd);
            lds_barrier();
        }

        // fc head: out[b] = fc2 . relu(fc1 @ h1_last + b1) + b2
        vm_drain();
        __syncthreads();
        const int g = tid >> 5;
        const int l = tid & 31;
        const float4* h4 = (const float4*)(h1s + (size_t)(p * 16 + g) * NH);
        const float4* w0 = (const float4*)(fc1w + (size_t)l * NH);
        const float4* w1 = (const float4*)(fc1w + (size_t)(l + 32) * NH);
        float a0 = fc1b[l], a1 = fc1b[l + 32];
#pragma unroll
        for (int q = 0; q < 32; ++q) {
            float4 h = h4[q], u = w0[q], v = w1[q];
            a0 += u.x * h.x + u.y * h.y + u.z * h.z + u.w * h.w;
            a1 += v.x * h.x + v.y * h.y + v.z * h.z + v.w * h.w;
        }
        float pv = fc2w[l] * fmaxf(a0, 0.f) + fc2w[l + 32] * fmaxf(a1, 0.f);
#pragma unroll
        for (int off = 16; off > 0; off >>= 1) pv += __shfl_down(pv, off, 32);
        if (l == 0) out[p * 16 + g] = pv + fc2b[0];
    }
}

extern "C" void kernel_launch(void* const* d_in, const int* in_sizes, int n_in,
                              void* d_out, int out_size, void* d_ws, size_t ws_size,
                              hipStream_t stream)
{
    const float* x     = (const float*)d_in[0];
    const float* w_ih0 = (const float*)d_in[1];
    const float* w_hh0 = (const float*)d_in[2];
    const float* b_ih0 = (const float*)d_in[3];
    const float* b_hh0 = (const float*)d_in[4];
    const float* w_ih1 = (const float*)d_in[5];
    const float* w_hh1 = (const float*)d_in[6];
    const float* b_ih1 = (const float*)d_in[7];
    const float* b_hh1 = (const float*)d_in[8];
    const float* fc1w  = (const float*)d_in[9];
    const float* fc1b  = (const float*)d_in[10];
    const float* fc2w  = (const float*)d_in[11];
    const float* fc2b  = (const float*)d_in[12];
    float* out = (float*)d_out;
    float* ws  = (float*)d_ws;

    // ws layout (floats):
    //  h0 planes: 256 t x 2 pl x 32 p x 4KB  = 16.78M floats (64 MB)
    //  xg ring  : RING x 32 p x WIN x 8192   = 16.78M floats (64 MB)
    //  h1s 64K | flags 3072 u32  -> total ~134.5 MB (<= proven 152 MB ws)
    size_t o_h0  = 0;
    size_t o_xgr = o_h0 + (size_t)256 * 2 * 32 * 1024;   // u64 count*2 floats
    size_t o_h1s = o_xgr + (size_t)RING * 32 * WIN * 8192;
    size_t o_flg = o_h1s + (size_t)NB * NH;

    u64*      h0pl = (u64*)(ws + o_h0);
    float*    xgr  = ws + o_xgr;
    float*    h1sp = ws + o_h1s;
    unsigned* ctr0 = (unsigned*)(ws + o_flg);
    unsigned* flagW = ctr0 + 32 * 16;
    unsigned* ctr1  = flagW + 32 * 64;

    hipMemsetAsync(ctr0, 0, (32 * 16 + 32 * 64 + 32 * 16) * sizeof(unsigned),
                   stream);

    void* args[] = {
        (void*)&x,
        (void*)&w_hh0, (void*)&w_hh1,
        (void*)&w_ih0, (void*)&b_ih0, (void*)&b_hh0,
        (void*)&w_ih1, (void*)&b_ih1, (void*)&b_hh1,
        (void*)&fc1w, (void*)&fc1b, (void*)&fc2w, (void*)&fc2b,
        (void*)&h0pl, (void*)&xgr, (void*)&h1sp, (void*)&out,
        (void*)&ctr0, (void*)&flagW, (void*)&ctr1,
    };
    hipLaunchCooperativeKernel((const void*)fused, dim3(256), dim3(512),
                               args, 0, stream);
}